// Round 7
// baseline (370.005 us; speedup 1.0000x reference)
//
#include <hip/hip_runtime.h>
#include <hip/hip_bf16.h>
#include <stdint.h>

#define EMB 1024
#define HEADS 16
#define HDIM 64
#define BATCH 4
#define SEQ 2048
#define MTOT (BATCH * SEQ) /* 8192 */

typedef unsigned short u16;
typedef __attribute__((ext_vector_type(8))) short bf16x8;
typedef __attribute__((ext_vector_type(4))) float f32x4;

__device__ inline u16 f2bf(float f) {
    uint32_t u = __builtin_bit_cast(uint32_t, f);
    u += 0x7fffu + ((u >> 16) & 1u);  // RNE; inputs are finite
    return (u16)(u >> 16);
}

// pack 2 f32 -> 2 bf16 via compiler intrinsic (RNE; a in low half)
__device__ inline uint32_t pkbf(float a, float b) {
    __hip_bfloat162 h = __float22bfloat162_rn(make_float2(a, b));
    uint32_t r;
    __builtin_memcpy(&r, &h, 4);
    return r;
}

__device__ inline f32x4 mfma16(bf16x8 a, bf16x8 b, f32x4 c) {
    return __builtin_amdgcn_mfma_f32_16x16x32_bf16(a, b, c, 0, 0, 0);
}

#define GLDS16(gp, lp)                                                        \
    __builtin_amdgcn_global_load_lds(                                         \
        (const __attribute__((address_space(1))) void*)(gp),                  \
        (__attribute__((address_space(3))) void*)(lp), 16, 0, 0)

// ------ mask compaction: per batch, list of active key positions ----------
// cnt[b] = #active; idx[b][j] = source row of compacted key j (j < cnt).
__global__ void mask_compact(const int* __restrict__ mask,
                             int* __restrict__ cnt, int* __restrict__ idx) {
    __shared__ int ps[256];
    const int b = blockIdx.x, tid = threadIdx.x;
    const int* mp = mask + (size_t)b * SEQ;
    int m[8], s = 0;
#pragma unroll
    for (int e = 0; e < 8; ++e) {
        m[e] = mp[tid * 8 + e] ? 1 : 0;
        s += m[e];
    }
    ps[tid] = s;
    __syncthreads();
    for (int off = 1; off < 256; off <<= 1) {
        int v = (tid >= off) ? ps[tid - off] : 0;
        __syncthreads();
        if (tid >= off) ps[tid] += v;
        __syncthreads();
    }
    const int total = ps[255];
    int r = ps[tid] - s;  // exclusive prefix
#pragma unroll
    for (int e = 0; e < 8; ++e)
        if (m[e]) idx[b * SEQ + r++] = tid * 8 + e;
    if (tid == 0) cnt[b] = total;
}

// ------ gather active rows + cast f32->bf16 (key/value inputs) ------------
// dst row (b, j): j < cnt -> src row idx[b][j]; cnt<=j<cntp -> zeros;
// j >= cntp -> untouched (never read downstream).
__global__ void gather_cast(const float* __restrict__ src,
                            const int* __restrict__ idx,
                            const int* __restrict__ cnt,
                            u16* __restrict__ dst) {
    const int row = blockIdx.x;  // 0..MTOT-1
    const int b = row >> 11, j = row & (SEQ - 1);
    const int cn = cnt[b];
    const int cp = (cn + 127) & ~127;
    if (j >= cp) return;
    const int c4 = threadIdx.x;  // 0..255 = EMB/4
    float4 v = {0.f, 0.f, 0.f, 0.f};
    if (j < cn) {
        const int srow = idx[b * SEQ + j];
        v = ((const float4*)(src + (size_t)(b * SEQ + srow) * EMB))[c4];
    }
    ushort4 o;
    o.x = f2bf(v.x); o.y = f2bf(v.y); o.z = f2bf(v.z); o.w = f2bf(v.w);
    ((ushort4*)(dst + (size_t)row * EMB))[c4] = o;
}

// ---------------- cast f32 -> bf16 (vectorized) ----------------
__global__ void cast_f32_bf16(const float* __restrict__ src,
                              u16* __restrict__ dst, int n4) {
    int i = blockIdx.x * blockDim.x + threadIdx.x;
    if (i >= n4) return;
    float4 v = ((const float4*)src)[i];
    ushort4 o;
    o.x = f2bf(v.x); o.y = f2bf(v.y); o.z = f2bf(v.z); o.w = f2bf(v.w);
    ((ushort4*)dst)[i] = o;
}

// ---------------- transpose + cast W (EMB x EMB): Wt[n][k] = W[k][n] -------
__global__ void transpose_cast(const float* __restrict__ W,
                               u16* __restrict__ Wt) {
    __shared__ u16 T[64][65];
    const int kb = blockIdx.y * 64, nb = blockIdx.x * 64;
    const int tr = threadIdx.x >> 4;         // 0..15
    const int tc = (threadIdx.x & 15) * 4;   // 0..60
#pragma unroll
    for (int j = 0; j < 4; ++j) {
        int r = tr + j * 16;
        float4 v = *(const float4*)&W[(size_t)(kb + r) * EMB + nb + tc];
        T[tc + 0][r] = f2bf(v.x);
        T[tc + 1][r] = f2bf(v.y);
        T[tc + 2][r] = f2bf(v.z);
        T[tc + 3][r] = f2bf(v.w);
    }
    __syncthreads();
#pragma unroll
    for (int j = 0; j < 4; ++j) {
        int rr = tr + j * 16;
        ushort4 o;
        o.x = T[rr][tc]; o.y = T[rr][tc + 1];
        o.z = T[rr][tc + 2]; o.w = T[rr][tc + 3];
        *(ushort4*)&Wt[(size_t)(nb + rr) * EMB + kb + tc] = o;
    }
}

// ------- transpose V per head, PV-permuted: Vp[b][s][h*64+d] -> Vt --------
// Within each 32-key group, key k (quad=(k&15)>>2, r=k&3, half=k>>4) is
// stored at position quad*8 + r + 4*half -> PV A-operand is one b128 read.
// Early-exits blocks beyond the batch's padded active-key count.
__global__ void transpose_v(const u16* __restrict__ Vp, u16* __restrict__ Vt,
                            const int* __restrict__ cnt) {
    __shared__ u16 T[64][65];
    const int h = blockIdx.x;           // 0..15 (one head = 64 cols)
    const int b = blockIdx.y >> 5;      // /(SEQ/64)
    const int s0 = (blockIdx.y & 31) * 64;
    const int cp = (cnt[b] + 127) & ~127;
    if (s0 >= cp) return;
    const int tr = threadIdx.x >> 3;    // 0..31
    const int tc = (threadIdx.x & 7) * 8;
#pragma unroll
    for (int j = 0; j < 2; ++j) {
        int sr = tr + j * 32;
        uint4 v = *(const uint4*)&Vp[(size_t)(b * SEQ + s0 + sr) * EMB +
                                     h * 64 + tc];
        const u16* p = (const u16*)&v;
#pragma unroll
        for (int e = 0; e < 8; ++e) T[tc + e][sr] = p[e];
    }
    __syncthreads();
#pragma unroll
    for (int j = 0; j < 2; ++j) {
        int d = tr + j * 32;
        u16 tmp[8];
#pragma unroll
        for (int e = 0; e < 8; ++e) tmp[e] = T[d][tc + e];
        const int base32 = s0 + (tc & 32);
        const int p0 = ((tc & 8) << 1) + ((tc & 16) >> 2);
        const size_t rowoff =
            ((size_t)(b * HEADS + h) * HDIM + d) * SEQ;
        *(uint2*)&Vt[rowoff + base32 + p0] = *(const uint2*)&tmp[0];
        *(uint2*)&Vt[rowoff + base32 + p0 + 8] = *(const uint2*)&tmp[4];
    }
}

// ------- GEMM: C[M][N] = (A[M][K] @ Bt[N][K]^T + bias) * scale -------------
// Optional cnt: M is batch-blocked (SEQ rows/batch); blocks whose 128-row
// tile lies beyond the batch's padded active count exit immediately.
template <bool OUT_BF16>
__global__ __launch_bounds__(256, 2) void gemm_bt(
    const u16* __restrict__ A, const u16* __restrict__ Bt,
    const float* __restrict__ bias, void* __restrict__ C,
    int M, int N, int K, float scale, const int* __restrict__ cnt) {
    __shared__ __align__(16) u16 As[128 * 32];
    __shared__ __align__(16) u16 Bs[128 * 32];
    const int m0 = blockIdx.y * 128, n0 = blockIdx.x * 128;
    if (cnt) {
        const int bb = m0 >> 11;
        const int cp = (cnt[bb] + 127) & ~127;
        if ((m0 & (SEQ - 1)) >= cp) return;
    }
    const int tid = threadIdx.x;
    const int w = tid >> 6, l = tid & 63;
    const int quad = l >> 4, l16 = l & 15;
    const int wm = (w >> 1) * 64, wn = (w & 1) * 64;

    f32x4 acc[4][4];
#pragma unroll
    for (int i = 0; i < 4; ++i)
#pragma unroll
        for (int j = 0; j < 4; ++j) acc[i][j] = (f32x4){0.f, 0.f, 0.f, 0.f};

    for (int k0 = 0; k0 < K; k0 += 32) {
        __syncthreads();
#pragma unroll
        for (int i = 0; i < 2; ++i) {
            int c = (w * 2 + i) * 64 + l;            // lds chunk, lane-contig
            int r = c >> 2;
            int sc = (c & 3) ^ ((r >> 1) & 3);       // global chunk (swizzle)
            GLDS16(A + (size_t)(m0 + r) * K + k0 + sc * 8, &As[c * 8]);
            GLDS16(Bt + (size_t)(n0 + r) * K + k0 + sc * 8, &Bs[c * 8]);
        }
        __syncthreads();
        bf16x8 af[4], bfr[4];
#pragma unroll
        for (int mt = 0; mt < 4; ++mt) {
            int ra = wm + mt * 16 + l16;
            af[mt] = *(const bf16x8*)&As[ra * 32 +
                                         ((quad ^ ((ra >> 1) & 3)) * 8)];
        }
#pragma unroll
        for (int nt = 0; nt < 4; ++nt) {
            int rb = wn + nt * 16 + l16;
            bfr[nt] = *(const bf16x8*)&Bs[rb * 32 +
                                          ((quad ^ ((rb >> 1) & 3)) * 8)];
        }
#pragma unroll
        for (int mt = 0; mt < 4; ++mt)
#pragma unroll
            for (int nt = 0; nt < 4; ++nt)
                acc[mt][nt] = mfma16(af[mt], bfr[nt], acc[mt][nt]);
    }

#pragma unroll
    for (int mt = 0; mt < 4; ++mt) {
#pragma unroll
        for (int nt = 0; nt < 4; ++nt) {
            int col = n0 + wn + nt * 16 + l16;
            float bv = bias[col];
#pragma unroll
            for (int r = 0; r < 4; ++r) {
                int row = m0 + wm + mt * 16 + quad * 4 + r;
                float v = (acc[mt][nt][r] + bv) * scale;
                if (OUT_BF16)
                    ((u16*)C)[(size_t)row * N + col] = f2bf(v);
                else
                    ((float*)C)[(size_t)row * N + col] = v;
            }
        }
    }
}

// ------ flash attention over COMPACTED keys: Q-tile 128, S^T scores -------
// Q pre-scaled by 1/sqrt(d)*log2(e) in its GEMM epilogue -> exp2(s) direct;
// last key tile's pads masked by register compare vs cnt. Row-sum l on the
// MFMA pipe (all-ones A fragment). K staged in LDS (dbuf, 32 KB);
// V read direct from global (L2-resident). ISSUE ORDER (pinned by
// sched_barrier): V-loads FIRST (oldest in vmcnt queue -> PV waits
// vmcnt(4), not 0), then K-DMA for t+1 (stays in flight across the tile),
// then QK^T. Round-6 failed both ways: compiler sank the V hoists
// (VGPR=100 proved it) and V-after-DMA order forced vmcnt(0).
// launch_bounds(256,2): NOT 4 -- arg2=4 capped VGPR=64 -> 600 MB spill (r4).
__global__ __launch_bounds__(256, 2) void attn_kernel(
    const u16* __restrict__ Qp, const u16* __restrict__ Kp,
    const u16* __restrict__ Vt, const int* __restrict__ cnt,
    u16* __restrict__ attnb) {
    __shared__ __align__(16) u16 Ks[2][128 * 64];    // 32 KB total

    const int tid = threadIdx.x;
    const int w = tid >> 6, l = tid & 63;
    const int quad = l >> 4, l16 = l & 15;

    const int nqb = SEQ / 128;  // 16
    const int qb = blockIdx.x % nqb;
    const int bh = blockIdx.x / nqb;
    const int b = bh / HEADS, h = bh % HEADS;
    const int q0 = qb * 128;
    const size_t head_off = (size_t)b * SEQ * EMB + (size_t)h * HDIM;
    const size_t vt_off = (size_t)bh * HDIM * SEQ;

    const int cn = cnt[b];
    const int ntile = ((cn + 127) & ~127) >> 7;  // >=1 (mask has actives)

    auto stageK = [&](int buf, int t) {
#pragma unroll
        for (int i = 0; i < 4; ++i) {
            int c = (w * 4 + i) * 64 + l;
            int r = c >> 3;
            int sc = (c & 7) ^ (r & 7);
            GLDS16(Kp + head_off + (size_t)(t * 128 + r) * EMB + sc * 8,
                   &Ks[buf][c * 8]);
        }
    };

    // Q fragments direct global->VGPR (one-time)
    bf16x8 bq[2][2];
#pragma unroll
    for (int g = 0; g < 2; ++g) {
        const u16* qrow =
            Qp + head_off + (size_t)(q0 + w * 32 + g * 16 + l16) * EMB;
        bq[g][0] = *(const bf16x8*)(qrow + quad * 8);
        bq[g][1] = *(const bf16x8*)(qrow + 32 + quad * 8);
    }

    // all-ones bf16 A fragment for row-sum MFMA
    bf16x8 ones;
#pragma unroll
    for (int e = 0; e < 8; ++e) ones[e] = (short)0x3f80;

    // prefetch tile 0
    stageK(0, 0);
    __syncthreads();  // K(0) visible

    f32x4 OA[4], OB[4];
#pragma unroll
    for (int i = 0; i < 4; ++i) {
        OA[i] = (f32x4){0.f, 0.f, 0.f, 0.f};
        OB[i] = (f32x4){0.f, 0.f, 0.f, 0.f};
    }
    f32x4 LA = (f32x4){0.f, 0.f, 0.f, 0.f};
    f32x4 LB = (f32x4){0.f, 0.f, 0.f, 0.f};

    auto tilebody = [&](int t, bool last) {
        const int cur = t & 1;
        const u16* ksb = Ks[cur];
        const u16* vtg = Vt + vt_off + t * 128;  // global V, PV-permuted

        // (1) V fragment loads FIRST -- oldest in the vmcnt queue
        bf16x8 va[4][4];
#pragma unroll
        for (int dt = 0; dt < 4; ++dt) {
            int vd = dt * 16 + l16;
#pragma unroll
            for (int i = 0; i < 4; ++i)
                va[dt][i] = *(const bf16x8*)&vtg[(size_t)vd * SEQ +
                                                 (4 * i + quad) * 8];
        }
        __builtin_amdgcn_sched_barrier(0);  // pin: V issued before K-DMA

        // (2) async K prefetch for t+1 (in flight across whole tile)
        if (!last) stageK(cur ^ 1, t + 1);
        __builtin_amdgcn_sched_barrier(0);  // pin: loads before compute

        // (3) S^T + exp + pack, both q groups sharing K fragments
        uint32_t pk[2][8][2];
#pragma unroll
        for (int nt = 0; nt < 8; ++nt) {
            int rk = nt * 16 + l16;
            bf16x8 ka0 =
                *(const bf16x8*)&ksb[rk * 64 + ((quad ^ (rk & 7)) * 8)];
            bf16x8 ka1 =
                *(const bf16x8*)&ksb[rk * 64 + (((quad + 4) ^ (rk & 7)) * 8)];
#pragma unroll
            for (int g = 0; g < 2; ++g) {
                f32x4 s = (f32x4){0.f, 0.f, 0.f, 0.f};
                s = mfma16(ka0, bq[g][0], s);  // A=K, B=Q -> S^T
                s = mfma16(ka1, bq[g][1], s);
                f32x4 p;
                if (last) {
                    const int kb = t * 128 + nt * 16 + quad * 4;
#pragma unroll
                    for (int r = 0; r < 4; ++r)
                        p[r] = __builtin_amdgcn_exp2f(
                            (kb + r < cn) ? s[r] : -30000.f);
                } else {
#pragma unroll
                    for (int r = 0; r < 4; ++r)
                        p[r] = __builtin_amdgcn_exp2f(s[r]);
                }
                pk[g][nt][0] = pkbf(p[0], p[1]);
                pk[g][nt][1] = pkbf(p[2], p[3]);
            }
        }

        // (4) O^T += V^T·P^T from registers; l += 1^T·P^T on the MFMA pipe
#pragma unroll
        for (int i = 0; i < 4; ++i) {
            union { bf16x8 v; uint32_t u[4]; } bpA, bpB;
            bpA.u[0] = pk[0][2 * i][0];
            bpA.u[1] = pk[0][2 * i][1];
            bpA.u[2] = pk[0][2 * i + 1][0];
            bpA.u[3] = pk[0][2 * i + 1][1];
            bpB.u[0] = pk[1][2 * i][0];
            bpB.u[1] = pk[1][2 * i][1];
            bpB.u[2] = pk[1][2 * i + 1][0];
            bpB.u[3] = pk[1][2 * i + 1][1];
            LA = mfma16(ones, bpA.v, LA);
            LB = mfma16(ones, bpB.v, LB);
#pragma unroll
            for (int dt = 0; dt < 4; ++dt) {
                OA[dt] = mfma16(va[dt][i], bpA.v, OA[dt]);
                OB[dt] = mfma16(va[dt][i], bpB.v, OB[dt]);
            }
        }

        __syncthreads();  // drains own DMA+ds_reads, then syncs (dbuf safety)
    };

    for (int t = 0; t < ntile - 1; ++t) tilebody(t, false);
    tilebody(ntile - 1, true);

    // epilogue: O[q][d] = O^T[d][q]/l; lane: q=l16, d=dt*16+quad*4+r
    // LA/LB rows are all equal (A=ones), so l = LA[0]/LB[0].
#pragma unroll
    for (int g = 0; g < 2; ++g) {
        float inv = 1.0f / (g == 0 ? LA[0] : LB[0]);
        const f32x4* O = (g == 0) ? OA : OB;
        const int orow = q0 + w * 32 + g * 16 + l16;
#pragma unroll
        for (int dt = 0; dt < 4; ++dt) {
            ushort4 o;
            o.x = f2bf(O[dt][0] * inv);
            o.y = f2bf(O[dt][1] * inv);
            o.z = f2bf(O[dt][2] * inv);
            o.w = f2bf(O[dt][3] * inv);
            *(uint2*)&attnb[head_off + (size_t)orow * EMB + dt * 16 +
                            quad * 4] = *(uint2*)&o;
        }
    }
}

extern "C" void kernel_launch(void* const* d_in, const int* in_sizes, int n_in,
                              void* d_out, int out_size, void* d_ws,
                              size_t ws_size, hipStream_t stream) {
    const float* query = (const float*)d_in[0];
    const float* key = (const float*)d_in[1];
    const float* value = (const float*)d_in[2];
    const int* mask = (const int*)d_in[3];
    const float* Wq = (const float*)d_in[4];
    const float* bq = (const float*)d_in[5];
    const float* Wk = (const float*)d_in[6];
    const float* bk = (const float*)d_in[7];
    const float* Wv = (const float*)d_in[8];
    const float* bv = (const float*)d_in[9];
    const float* Wo = (const float*)d_in[10];
    const float* bo = (const float*)d_in[11];

    char* ws = (char*)d_ws;
    const size_t MB = 1ull << 20;
    u16* xq = (u16*)(ws + 0 * MB);     // 16 MB; dead after Q-GEMM -> reused as Vt
    u16* xk = (u16*)(ws + 16 * MB);    // compacted key rows (bf16)
    u16* xv = (u16*)(ws + 32 * MB);    // compacted value rows (bf16)
    u16* Wqt = (u16*)(ws + 48 * MB);   // 2 MB each
    u16* Wkt = (u16*)(ws + 50 * MB);
    u16* Wvt = (u16*)(ws + 52 * MB);
    u16* Wot = (u16*)(ws + 54 * MB);
    u16* Qp = (u16*)(ws + 56 * MB);
    u16* Kp = (u16*)(ws + 72 * MB);
    u16* Vp = (u16*)(ws + 88 * MB);
    u16* attnb = (u16*)(ws + 104 * MB);  // total 120 MB
    u16* Vt = xq;                        // Vt[b][h][d][s-permuted], 16 MB

    // compaction scratch lives in d_out (fully overwritten by O-GEMM later)
    int* cnt = (int*)d_out;                      // 4 ints
    int* idx = (int*)d_out + 64;                 // MTOT ints

    mask_compact<<<BATCH, 256, 0, stream>>>(mask, cnt, idx);

    const int n4 = MTOT * EMB / 4;
    cast_f32_bf16<<<(n4 + 255) / 256, 256, 0, stream>>>(query, xq, n4);
    gather_cast<<<MTOT, 256, 0, stream>>>(key, idx, cnt, xk);
    gather_cast<<<MTOT, 256, 0, stream>>>(value, idx, cnt, xv);

    dim3 tgrid(EMB / 64, EMB / 64);
    transpose_cast<<<tgrid, 256, 0, stream>>>(Wq, Wqt);
    transpose_cast<<<tgrid, 256, 0, stream>>>(Wk, Wkt);
    transpose_cast<<<tgrid, 256, 0, stream>>>(Wv, Wvt);
    transpose_cast<<<tgrid, 256, 0, stream>>>(Wo, Wot);

    const float c2 = 0.125f * 1.44269504f;  // 1/sqrt(64) * log2(e)
    dim3 ggrid(EMB / 128, MTOT / 128);  // (8, 64)
    gemm_bt<true><<<ggrid, 256, 0, stream>>>(xq, Wqt, bq, Qp, MTOT, EMB, EMB,
                                             c2, nullptr);
    gemm_bt<true><<<ggrid, 256, 0, stream>>>(xk, Wkt, bk, Kp, MTOT, EMB, EMB,
                                             1.0f, cnt);
    gemm_bt<true><<<ggrid, 256, 0, stream>>>(xv, Wvt, bv, Vp, MTOT, EMB, EMB,
                                             1.0f, cnt);

    // V^T once per element, PV-permuted key order (compacted key space)
    transpose_v<<<dim3(HEADS, MTOT / 64), 256, 0, stream>>>(Vp, Vt, cnt);

    attn_kernel<<<BATCH * HEADS * (SEQ / 128), 256, 0, stream>>>(Qp, Kp, Vt,
                                                                 cnt, attnb);

    gemm_bt<false><<<ggrid, 256, 0, stream>>>(attnb, Wot, bo, d_out, MTOT, EMB,
                                              EMB, 1.0f, nullptr);
}

// Round 8
// 345.389 us; speedup vs baseline: 1.0713x; 1.0713x over previous
//
#include <hip/hip_runtime.h>
#include <hip/hip_bf16.h>
#include <stdint.h>

#define EMB 1024
#define HEADS 16
#define HDIM 64
#define BATCH 4
#define SEQ 2048
#define MTOT (BATCH * SEQ) /* 8192 */

typedef unsigned short u16;
typedef __attribute__((ext_vector_type(8))) short bf16x8;
typedef __attribute__((ext_vector_type(4))) float f32x4;

__device__ inline u16 f2bf(float f) {
    uint32_t u = __builtin_bit_cast(uint32_t, f);
    u += 0x7fffu + ((u >> 16) & 1u);  // RNE; inputs are finite
    return (u16)(u >> 16);
}

// pack 2 f32 -> 2 bf16 via compiler intrinsic (RNE; a in low half)
__device__ inline uint32_t pkbf(float a, float b) {
    __hip_bfloat162 h = __float22bfloat162_rn(make_float2(a, b));
    uint32_t r;
    __builtin_memcpy(&r, &h, 4);
    return r;
}

__device__ inline f32x4 mfma16(bf16x8 a, bf16x8 b, f32x4 c) {
    return __builtin_amdgcn_mfma_f32_16x16x32_bf16(a, b, c, 0, 0, 0);
}

#define GLDS16(gp, lp)                                                        \
    __builtin_amdgcn_global_load_lds(                                         \
        (const __attribute__((address_space(1))) void*)(gp),                  \
        (__attribute__((address_space(3))) void*)(lp), 16, 0, 0)

// ------ mask compaction: per batch, list of active key positions ----------
// cnt[b] = #active; idx[b][j] = source row of compacted key j (j < cnt).
__global__ void mask_compact(const int* __restrict__ mask,
                             int* __restrict__ cnt, int* __restrict__ idx) {
    __shared__ int ps[256];
    const int b = blockIdx.x, tid = threadIdx.x;
    const int* mp = mask + (size_t)b * SEQ;
    int m[8], s = 0;
#pragma unroll
    for (int e = 0; e < 8; ++e) {
        m[e] = mp[tid * 8 + e] ? 1 : 0;
        s += m[e];
    }
    ps[tid] = s;
    __syncthreads();
    for (int off = 1; off < 256; off <<= 1) {
        int v = (tid >= off) ? ps[tid - off] : 0;
        __syncthreads();
        if (tid >= off) ps[tid] += v;
        __syncthreads();
    }
    const int total = ps[255];
    int r = ps[tid] - s;  // exclusive prefix
#pragma unroll
    for (int e = 0; e < 8; ++e)
        if (m[e]) idx[b * SEQ + r++] = tid * 8 + e;
    if (tid == 0) cnt[b] = total;
}

// ------ gather active rows + cast f32->bf16 (key/value inputs) ------------
// dst row (b, j): j < cnt -> src row idx[b][j]; cnt<=j<cntp -> zeros;
// j >= cntp -> untouched (never read downstream).
__global__ void gather_cast(const float* __restrict__ src,
                            const int* __restrict__ idx,
                            const int* __restrict__ cnt,
                            u16* __restrict__ dst) {
    const int row = blockIdx.x;  // 0..MTOT-1
    const int b = row >> 11, j = row & (SEQ - 1);
    const int cn = cnt[b];
    const int cp = (cn + 127) & ~127;
    if (j >= cp) return;
    const int c4 = threadIdx.x;  // 0..255 = EMB/4
    float4 v = {0.f, 0.f, 0.f, 0.f};
    if (j < cn) {
        const int srow = idx[b * SEQ + j];
        v = ((const float4*)(src + (size_t)(b * SEQ + srow) * EMB))[c4];
    }
    ushort4 o;
    o.x = f2bf(v.x); o.y = f2bf(v.y); o.z = f2bf(v.z); o.w = f2bf(v.w);
    ((ushort4*)(dst + (size_t)row * EMB))[c4] = o;
}

// ---------------- cast f32 -> bf16 (vectorized) ----------------
__global__ void cast_f32_bf16(const float* __restrict__ src,
                              u16* __restrict__ dst, int n4) {
    int i = blockIdx.x * blockDim.x + threadIdx.x;
    if (i >= n4) return;
    float4 v = ((const float4*)src)[i];
    ushort4 o;
    o.x = f2bf(v.x); o.y = f2bf(v.y); o.z = f2bf(v.z); o.w = f2bf(v.w);
    ((ushort4*)dst)[i] = o;
}

// ---------------- transpose + cast W (EMB x EMB): Wt[n][k] = W[k][n] -------
__global__ void transpose_cast(const float* __restrict__ W,
                               u16* __restrict__ Wt) {
    __shared__ u16 T[64][65];
    const int kb = blockIdx.y * 64, nb = blockIdx.x * 64;
    const int tr = threadIdx.x >> 4;         // 0..15
    const int tc = (threadIdx.x & 15) * 4;   // 0..60
#pragma unroll
    for (int j = 0; j < 4; ++j) {
        int r = tr + j * 16;
        float4 v = *(const float4*)&W[(size_t)(kb + r) * EMB + nb + tc];
        T[tc + 0][r] = f2bf(v.x);
        T[tc + 1][r] = f2bf(v.y);
        T[tc + 2][r] = f2bf(v.z);
        T[tc + 3][r] = f2bf(v.w);
    }
    __syncthreads();
#pragma unroll
    for (int j = 0; j < 4; ++j) {
        int rr = tr + j * 16;
        ushort4 o;
        o.x = T[rr][tc]; o.y = T[rr][tc + 1];
        o.z = T[rr][tc + 2]; o.w = T[rr][tc + 3];
        *(ushort4*)&Wt[(size_t)(nb + rr) * EMB + kb + tc] = o;
    }
}

// ------- transpose V per head, PV-permuted: Vp[b][s][h*64+d] -> Vt --------
// Within each 32-key group, key k (quad=(k&15)>>2, r=k&3, half=k>>4) is
// stored at position quad*8 + r + 4*half -> PV A-operand is one b128 read.
// Early-exits blocks beyond the batch's padded active-key count.
__global__ void transpose_v(const u16* __restrict__ Vp, u16* __restrict__ Vt,
                            const int* __restrict__ cnt) {
    __shared__ u16 T[64][65];
    const int h = blockIdx.x;           // 0..15 (one head = 64 cols)
    const int b = blockIdx.y >> 5;      // /(SEQ/64)
    const int s0 = (blockIdx.y & 31) * 64;
    const int cp = (cnt[b] + 127) & ~127;
    if (s0 >= cp) return;
    const int tr = threadIdx.x >> 3;    // 0..31
    const int tc = (threadIdx.x & 7) * 8;
#pragma unroll
    for (int j = 0; j < 2; ++j) {
        int sr = tr + j * 32;
        uint4 v = *(const uint4*)&Vp[(size_t)(b * SEQ + s0 + sr) * EMB +
                                     h * 64 + tc];
        const u16* p = (const u16*)&v;
#pragma unroll
        for (int e = 0; e < 8; ++e) T[tc + e][sr] = p[e];
    }
    __syncthreads();
#pragma unroll
    for (int j = 0; j < 2; ++j) {
        int d = tr + j * 32;
        u16 tmp[8];
#pragma unroll
        for (int e = 0; e < 8; ++e) tmp[e] = T[d][tc + e];
        const int base32 = s0 + (tc & 32);
        const int p0 = ((tc & 8) << 1) + ((tc & 16) >> 2);
        const size_t rowoff =
            ((size_t)(b * HEADS + h) * HDIM + d) * SEQ;
        *(uint2*)&Vt[rowoff + base32 + p0] = *(const uint2*)&tmp[0];
        *(uint2*)&Vt[rowoff + base32 + p0 + 8] = *(const uint2*)&tmp[4];
    }
}

// ------- GEMM: C[M][N] = (A[M][K] @ Bt[N][K]^T + bias) * scale -------------
// Optional cnt: M is batch-blocked (SEQ rows/batch); blocks whose 128-row
// tile lies beyond the batch's padded active count exit immediately.
template <bool OUT_BF16>
__global__ __launch_bounds__(256, 2) void gemm_bt(
    const u16* __restrict__ A, const u16* __restrict__ Bt,
    const float* __restrict__ bias, void* __restrict__ C,
    int M, int N, int K, float scale, const int* __restrict__ cnt) {
    __shared__ __align__(16) u16 As[128 * 32];
    __shared__ __align__(16) u16 Bs[128 * 32];
    const int m0 = blockIdx.y * 128, n0 = blockIdx.x * 128;
    if (cnt) {
        const int bb = m0 >> 11;
        const int cp = (cnt[bb] + 127) & ~127;
        if ((m0 & (SEQ - 1)) >= cp) return;
    }
    const int tid = threadIdx.x;
    const int w = tid >> 6, l = tid & 63;
    const int quad = l >> 4, l16 = l & 15;
    const int wm = (w >> 1) * 64, wn = (w & 1) * 64;

    f32x4 acc[4][4];
#pragma unroll
    for (int i = 0; i < 4; ++i)
#pragma unroll
        for (int j = 0; j < 4; ++j) acc[i][j] = (f32x4){0.f, 0.f, 0.f, 0.f};

    for (int k0 = 0; k0 < K; k0 += 32) {
        __syncthreads();
#pragma unroll
        for (int i = 0; i < 2; ++i) {
            int c = (w * 2 + i) * 64 + l;            // lds chunk, lane-contig
            int r = c >> 2;
            int sc = (c & 3) ^ ((r >> 1) & 3);       // global chunk (swizzle)
            GLDS16(A + (size_t)(m0 + r) * K + k0 + sc * 8, &As[c * 8]);
            GLDS16(Bt + (size_t)(n0 + r) * K + k0 + sc * 8, &Bs[c * 8]);
        }
        __syncthreads();
        bf16x8 af[4], bfr[4];
#pragma unroll
        for (int mt = 0; mt < 4; ++mt) {
            int ra = wm + mt * 16 + l16;
            af[mt] = *(const bf16x8*)&As[ra * 32 +
                                         ((quad ^ ((ra >> 1) & 3)) * 8)];
        }
#pragma unroll
        for (int nt = 0; nt < 4; ++nt) {
            int rb = wn + nt * 16 + l16;
            bfr[nt] = *(const bf16x8*)&Bs[rb * 32 +
                                          ((quad ^ ((rb >> 1) & 3)) * 8)];
        }
#pragma unroll
        for (int mt = 0; mt < 4; ++mt)
#pragma unroll
            for (int nt = 0; nt < 4; ++nt)
                acc[mt][nt] = mfma16(af[mt], bfr[nt], acc[mt][nt]);
    }

#pragma unroll
    for (int mt = 0; mt < 4; ++mt) {
#pragma unroll
        for (int nt = 0; nt < 4; ++nt) {
            int col = n0 + wn + nt * 16 + l16;
            float bv = bias[col];
#pragma unroll
            for (int r = 0; r < 4; ++r) {
                int row = m0 + wm + mt * 16 + quad * 4 + r;
                float v = (acc[mt][nt][r] + bv) * scale;
                if (OUT_BF16)
                    ((u16*)C)[(size_t)row * N + col] = f2bf(v);
                else
                    ((float*)C)[(size_t)row * N + col] = v;
            }
        }
    }
}

// ------ flash attention over COMPACTED keys: Q-tile 256, 8 waves ----------
// Round-2 data path (K AND V DMA-staged to LDS, double-buffered, 64 KB)
// but 512-thread blocks: 8 waves share each staged K/V tile across 256 q
// rows -> 2 blocks/CU = 16 waves/CU = 4 waves/SIMD (2x round-2's hiding),
// and K/V DMA issue per q-row halves. V-direct variants (r5-r7: 86-94us)
// lose to LDS-staged V (58us): strided 16B reads cost 16 lines/instr on
// the TA path with no TLP to cover. Q pre-scaled by 1/sqrt(d)*log2(e);
// pad keys masked by register compare vs cnt; row-sum l on the MFMA pipe.
// launch_bounds(512,2): arg2=4 capped VGPR=64 -> 600MB spill (r4 lesson).
__global__ __launch_bounds__(512, 2) void attn_kernel(
    const u16* __restrict__ Qp, const u16* __restrict__ Kp,
    const u16* __restrict__ Vt, const int* __restrict__ cnt,
    u16* __restrict__ attnb) {
    __shared__ __align__(16) u16 Ks[2][128 * 64];    // 32 KB
    __shared__ __align__(16) u16 Vts[2][64 * 128];   // 32 KB -> 64 KB total

    const int tid = threadIdx.x;
    const int w = tid >> 6, l = tid & 63;            // w: 0..7
    const int quad = l >> 4, l16 = l & 15;

    const int nqb = SEQ / 256;  // 8
    const int qb = blockIdx.x % nqb;
    const int bh = blockIdx.x / nqb;
    const int b = bh / HEADS, h = bh % HEADS;
    const int q0 = qb * 256;
    const size_t head_off = (size_t)b * SEQ * EMB + (size_t)h * HDIM;
    const size_t vt_off = (size_t)bh * HDIM * SEQ;

    const int cn = cnt[b];
    const int ntile = ((cn + 127) & ~127) >> 7;  // >=1 (mask has actives)

    auto stageKV = [&](int buf, int t) {
#pragma unroll
        for (int i = 0; i < 2; ++i) {                // 16 chunks over 8 waves
            int c = (w * 2 + i) * 64 + l;
            int r = c >> 3;
            int sc = (c & 7) ^ (r & 7);
            GLDS16(Kp + head_off + (size_t)(t * 128 + r) * EMB + sc * 8,
                   &Ks[buf][c * 8]);
        }
#pragma unroll
        for (int i = 0; i < 2; ++i) {
            int c = (w * 2 + i) * 64 + l;
            int r = c >> 4;
            int sc = (c & 15) ^ (r & 15);
            GLDS16(Vt + vt_off + (size_t)r * SEQ + t * 128 + sc * 8,
                   &Vts[buf][c * 8]);
        }
    };

    // Q fragments direct global->VGPR (one-time); wave owns 32 q rows
    bf16x8 bq[2][2];
#pragma unroll
    for (int g = 0; g < 2; ++g) {
        const u16* qrow =
            Qp + head_off + (size_t)(q0 + w * 32 + g * 16 + l16) * EMB;
        bq[g][0] = *(const bf16x8*)(qrow + quad * 8);
        bq[g][1] = *(const bf16x8*)(qrow + 32 + quad * 8);
    }

    // all-ones bf16 A fragment for row-sum MFMA
    bf16x8 ones;
#pragma unroll
    for (int e = 0; e < 8; ++e) ones[e] = (short)0x3f80;

    // prefetch tile 0
    stageKV(0, 0);
    __syncthreads();  // KV(0) visible

    f32x4 OA[4], OB[4];
#pragma unroll
    for (int i = 0; i < 4; ++i) {
        OA[i] = (f32x4){0.f, 0.f, 0.f, 0.f};
        OB[i] = (f32x4){0.f, 0.f, 0.f, 0.f};
    }
    f32x4 LA = (f32x4){0.f, 0.f, 0.f, 0.f};
    f32x4 LB = (f32x4){0.f, 0.f, 0.f, 0.f};

    auto tilebody = [&](int t, bool last) {
        const int cur = t & 1;
        if (!last) stageKV(cur ^ 1, t + 1);  // async prefetch
        const u16* ksb = Ks[cur];
        const u16* vsb = Vts[cur];

        // S^T + exp + pack, both q groups sharing K fragments
        uint32_t pk[2][8][2];
#pragma unroll
        for (int nt = 0; nt < 8; ++nt) {
            int rk = nt * 16 + l16;
            bf16x8 ka0 =
                *(const bf16x8*)&ksb[rk * 64 + ((quad ^ (rk & 7)) * 8)];
            bf16x8 ka1 =
                *(const bf16x8*)&ksb[rk * 64 + (((quad + 4) ^ (rk & 7)) * 8)];
#pragma unroll
            for (int g = 0; g < 2; ++g) {
                f32x4 s = (f32x4){0.f, 0.f, 0.f, 0.f};
                s = mfma16(ka0, bq[g][0], s);  // A=K, B=Q -> S^T
                s = mfma16(ka1, bq[g][1], s);
                f32x4 p;
                if (last) {
                    const int kb = t * 128 + nt * 16 + quad * 4;
#pragma unroll
                    for (int r = 0; r < 4; ++r)
                        p[r] = __builtin_amdgcn_exp2f(
                            (kb + r < cn) ? s[r] : -30000.f);
                } else {
#pragma unroll
                    for (int r = 0; r < 4; ++r)
                        p[r] = __builtin_amdgcn_exp2f(s[r]);
                }
                pk[g][nt][0] = pkbf(p[0], p[1]);
                pk[g][nt][1] = pkbf(p[2], p[3]);
            }
        }

        // O^T += V^T·P^T, V fragments shared across both q groups;
        // l += 1^T·P^T on the MFMA pipe
#pragma unroll
        for (int i = 0; i < 4; ++i) {
            union { bf16x8 v; uint32_t u[4]; } bpA, bpB;
            bpA.u[0] = pk[0][2 * i][0];
            bpA.u[1] = pk[0][2 * i][1];
            bpA.u[2] = pk[0][2 * i + 1][0];
            bpA.u[3] = pk[0][2 * i + 1][1];
            bpB.u[0] = pk[1][2 * i][0];
            bpB.u[1] = pk[1][2 * i][1];
            bpB.u[2] = pk[1][2 * i + 1][0];
            bpB.u[3] = pk[1][2 * i + 1][1];
            LA = mfma16(ones, bpA.v, LA);
            LB = mfma16(ones, bpB.v, LB);
#pragma unroll
            for (int dt = 0; dt < 4; ++dt) {
                int vd = dt * 16 + l16;
                bf16x8 ap = *(const bf16x8*)&vsb[vd * 128 +
                                                 (((4 * i + quad) ^ (vd & 15)) *
                                                  8)];
                OA[dt] = mfma16(ap, bpA.v, OA[dt]);
                OB[dt] = mfma16(ap, bpB.v, OB[dt]);
            }
        }

        __syncthreads();  // drains own DMA+ds_reads, then syncs (dbuf safety)
    };

    for (int t = 0; t < ntile - 1; ++t) tilebody(t, false);
    tilebody(ntile - 1, true);

    // epilogue: O[q][d] = O^T[d][q]/l; lane: q=l16, d=dt*16+quad*4+r
    // LA/LB rows are all equal (A=ones), so l = LA[0]/LB[0].
#pragma unroll
    for (int g = 0; g < 2; ++g) {
        float inv = 1.0f / (g == 0 ? LA[0] : LB[0]);
        const f32x4* O = (g == 0) ? OA : OB;
        const int orow = q0 + w * 32 + g * 16 + l16;
#pragma unroll
        for (int dt = 0; dt < 4; ++dt) {
            ushort4 o;
            o.x = f2bf(O[dt][0] * inv);
            o.y = f2bf(O[dt][1] * inv);
            o.z = f2bf(O[dt][2] * inv);
            o.w = f2bf(O[dt][3] * inv);
            *(uint2*)&attnb[head_off + (size_t)orow * EMB + dt * 16 +
                            quad * 4] = *(uint2*)&o;
        }
    }
}

extern "C" void kernel_launch(void* const* d_in, const int* in_sizes, int n_in,
                              void* d_out, int out_size, void* d_ws,
                              size_t ws_size, hipStream_t stream) {
    const float* query = (const float*)d_in[0];
    const float* key = (const float*)d_in[1];
    const float* value = (const float*)d_in[2];
    const int* mask = (const int*)d_in[3];
    const float* Wq = (const float*)d_in[4];
    const float* bq = (const float*)d_in[5];
    const float* Wk = (const float*)d_in[6];
    const float* bk = (const float*)d_in[7];
    const float* Wv = (const float*)d_in[8];
    const float* bv = (const float*)d_in[9];
    const float* Wo = (const float*)d_in[10];
    const float* bo = (const float*)d_in[11];

    char* ws = (char*)d_ws;
    const size_t MB = 1ull << 20;
    u16* xq = (u16*)(ws + 0 * MB);     // 16 MB; dead after Q-GEMM -> reused as Vt
    u16* xk = (u16*)(ws + 16 * MB);    // compacted key rows (bf16)
    u16* xv = (u16*)(ws + 32 * MB);    // compacted value rows (bf16)
    u16* Wqt = (u16*)(ws + 48 * MB);   // 2 MB each
    u16* Wkt = (u16*)(ws + 50 * MB);
    u16* Wvt = (u16*)(ws + 52 * MB);
    u16* Wot = (u16*)(ws + 54 * MB);
    u16* Qp = (u16*)(ws + 56 * MB);
    u16* Kp = (u16*)(ws + 72 * MB);
    u16* Vp = (u16*)(ws + 88 * MB);
    u16* attnb = (u16*)(ws + 104 * MB);  // total 120 MB
    u16* Vt = xq;                        // Vt[b][h][d][s-permuted], 16 MB

    // compaction scratch lives in d_out (fully overwritten by O-GEMM later)
    int* cnt = (int*)d_out;                      // 4 ints
    int* idx = (int*)d_out + 64;                 // MTOT ints

    mask_compact<<<BATCH, 256, 0, stream>>>(mask, cnt, idx);

    const int n4 = MTOT * EMB / 4;
    cast_f32_bf16<<<(n4 + 255) / 256, 256, 0, stream>>>(query, xq, n4);
    gather_cast<<<MTOT, 256, 0, stream>>>(key, idx, cnt, xk);
    gather_cast<<<MTOT, 256, 0, stream>>>(value, idx, cnt, xv);

    dim3 tgrid(EMB / 64, EMB / 64);
    transpose_cast<<<tgrid, 256, 0, stream>>>(Wq, Wqt);
    transpose_cast<<<tgrid, 256, 0, stream>>>(Wk, Wkt);
    transpose_cast<<<tgrid, 256, 0, stream>>>(Wv, Wvt);
    transpose_cast<<<tgrid, 256, 0, stream>>>(Wo, Wot);

    const float c2 = 0.125f * 1.44269504f;  // 1/sqrt(64) * log2(e)
    dim3 ggrid(EMB / 128, MTOT / 128);  // (8, 64)
    gemm_bt<true><<<ggrid, 256, 0, stream>>>(xq, Wqt, bq, Qp, MTOT, EMB, EMB,
                                             c2, nullptr);
    gemm_bt<true><<<ggrid, 256, 0, stream>>>(xk, Wkt, bk, Kp, MTOT, EMB, EMB,
                                             1.0f, cnt);
    gemm_bt<true><<<ggrid, 256, 0, stream>>>(xv, Wvt, bv, Vp, MTOT, EMB, EMB,
                                             1.0f, cnt);

    // V^T once per element, PV-permuted key order (compacted key space)
    transpose_v<<<dim3(HEADS, MTOT / 64), 256, 0, stream>>>(Vp, Vt, cnt);

    attn_kernel<<<BATCH * HEADS * (SEQ / 256), 512, 0, stream>>>(Qp, Kp, Vt,
                                                                 cnt, attnb);

    gemm_bt<false><<<ggrid, 256, 0, stream>>>(attnb, Wot, bo, d_out, MTOT, EMB,
                                              EMB, 1.0f, nullptr);
}

// Round 9
// 341.999 us; speedup vs baseline: 1.0819x; 1.0099x over previous
//
#include <hip/hip_runtime.h>
#include <hip/hip_bf16.h>
#include <stdint.h>

#define EMB 1024
#define HEADS 16
#define HDIM 64
#define BATCH 4
#define SEQ 2048
#define MTOT (BATCH * SEQ) /* 8192 */

typedef unsigned short u16;
typedef __attribute__((ext_vector_type(8))) short bf16x8;
typedef __attribute__((ext_vector_type(4))) float f32x4;

__device__ inline u16 f2bf(float f) {
    uint32_t u = __builtin_bit_cast(uint32_t, f);
    u += 0x7fffu + ((u >> 16) & 1u);  // RNE; inputs are finite
    return (u16)(u >> 16);
}

// pack 2 f32 -> 2 bf16 via compiler intrinsic (RNE; a in low half)
__device__ inline uint32_t pkbf(float a, float b) {
    __hip_bfloat162 h = __float22bfloat162_rn(make_float2(a, b));
    uint32_t r;
    __builtin_memcpy(&r, &h, 4);
    return r;
}

__device__ inline f32x4 mfma16(bf16x8 a, bf16x8 b, f32x4 c) {
    return __builtin_amdgcn_mfma_f32_16x16x32_bf16(a, b, c, 0, 0, 0);
}

#define GLDS16(gp, lp)                                                        \
    __builtin_amdgcn_global_load_lds(                                         \
        (const __attribute__((address_space(1))) void*)(gp),                  \
        (__attribute__((address_space(3))) void*)(lp), 16, 0, 0)

// ------ mask compaction: per batch, list of active key positions ----------
// cnt[b] = #active; idx[b][j] = source row of compacted key j (j < cnt).
__global__ void mask_compact(const int* __restrict__ mask,
                             int* __restrict__ cnt, int* __restrict__ idx) {
    __shared__ int ps[256];
    const int b = blockIdx.x, tid = threadIdx.x;
    const int* mp = mask + (size_t)b * SEQ;
    int m[8], s = 0;
#pragma unroll
    for (int e = 0; e < 8; ++e) {
        m[e] = mp[tid * 8 + e] ? 1 : 0;
        s += m[e];
    }
    ps[tid] = s;
    __syncthreads();
    for (int off = 1; off < 256; off <<= 1) {
        int v = (tid >= off) ? ps[tid - off] : 0;
        __syncthreads();
        if (tid >= off) ps[tid] += v;
        __syncthreads();
    }
    const int total = ps[255];
    int r = ps[tid] - s;  // exclusive prefix
#pragma unroll
    for (int e = 0; e < 8; ++e)
        if (m[e]) idx[b * SEQ + r++] = tid * 8 + e;
    if (tid == 0) cnt[b] = total;
}

// ------ gather active rows + cast f32->bf16 (key/value inputs) ------------
// dst row (b, j): j < cnt -> src row idx[b][j]; cnt<=j<cntp -> zeros;
// j >= cntp -> untouched (never read downstream).
__global__ void gather_cast(const float* __restrict__ src,
                            const int* __restrict__ idx,
                            const int* __restrict__ cnt,
                            u16* __restrict__ dst) {
    const int row = blockIdx.x;  // 0..MTOT-1
    const int b = row >> 11, j = row & (SEQ - 1);
    const int cn = cnt[b];
    const int cp = (cn + 127) & ~127;
    if (j >= cp) return;
    const int c4 = threadIdx.x;  // 0..255 = EMB/4
    float4 v = {0.f, 0.f, 0.f, 0.f};
    if (j < cn) {
        const int srow = idx[b * SEQ + j];
        v = ((const float4*)(src + (size_t)(b * SEQ + srow) * EMB))[c4];
    }
    ushort4 o;
    o.x = f2bf(v.x); o.y = f2bf(v.y); o.z = f2bf(v.z); o.w = f2bf(v.w);
    ((ushort4*)(dst + (size_t)row * EMB))[c4] = o;
}

// ---------------- cast f32 -> bf16 (vectorized) ----------------
__global__ void cast_f32_bf16(const float* __restrict__ src,
                              u16* __restrict__ dst, int n4) {
    int i = blockIdx.x * blockDim.x + threadIdx.x;
    if (i >= n4) return;
    float4 v = ((const float4*)src)[i];
    ushort4 o;
    o.x = f2bf(v.x); o.y = f2bf(v.y); o.z = f2bf(v.z); o.w = f2bf(v.w);
    ((ushort4*)dst)[i] = o;
}

// ---------------- transpose + cast W (EMB x EMB): Wt[n][k] = W[k][n] -------
__global__ void transpose_cast(const float* __restrict__ W,
                               u16* __restrict__ Wt) {
    __shared__ u16 T[64][65];
    const int kb = blockIdx.y * 64, nb = blockIdx.x * 64;
    const int tr = threadIdx.x >> 4;         // 0..15
    const int tc = (threadIdx.x & 15) * 4;   // 0..60
#pragma unroll
    for (int j = 0; j < 4; ++j) {
        int r = tr + j * 16;
        float4 v = *(const float4*)&W[(size_t)(kb + r) * EMB + nb + tc];
        T[tc + 0][r] = f2bf(v.x);
        T[tc + 1][r] = f2bf(v.y);
        T[tc + 2][r] = f2bf(v.z);
        T[tc + 3][r] = f2bf(v.w);
    }
    __syncthreads();
#pragma unroll
    for (int j = 0; j < 4; ++j) {
        int rr = tr + j * 16;
        ushort4 o;
        o.x = T[rr][tc]; o.y = T[rr][tc + 1];
        o.z = T[rr][tc + 2]; o.w = T[rr][tc + 3];
        *(ushort4*)&Wt[(size_t)(nb + rr) * EMB + kb + tc] = o;
    }
}

// ------- transpose V per head, PV-permuted: Vp[b][s][h*64+d] -> Vt --------
// Within each 32-key group, key k (quad=(k&15)>>2, r=k&3, half=k>>4) is
// stored at position quad*8 + r + 4*half -> PV A-operand is one b128 read.
// Early-exits blocks beyond the batch's padded active-key count.
__global__ void transpose_v(const u16* __restrict__ Vp, u16* __restrict__ Vt,
                            const int* __restrict__ cnt) {
    __shared__ u16 T[64][65];
    const int h = blockIdx.x;           // 0..15 (one head = 64 cols)
    const int b = blockIdx.y >> 5;      // /(SEQ/64)
    const int s0 = (blockIdx.y & 31) * 64;
    const int cp = (cnt[b] + 127) & ~127;
    if (s0 >= cp) return;
    const int tr = threadIdx.x >> 3;    // 0..31
    const int tc = (threadIdx.x & 7) * 8;
#pragma unroll
    for (int j = 0; j < 2; ++j) {
        int sr = tr + j * 32;
        uint4 v = *(const uint4*)&Vp[(size_t)(b * SEQ + s0 + sr) * EMB +
                                     h * 64 + tc];
        const u16* p = (const u16*)&v;
#pragma unroll
        for (int e = 0; e < 8; ++e) T[tc + e][sr] = p[e];
    }
    __syncthreads();
#pragma unroll
    for (int j = 0; j < 2; ++j) {
        int d = tr + j * 32;
        u16 tmp[8];
#pragma unroll
        for (int e = 0; e < 8; ++e) tmp[e] = T[d][tc + e];
        const int base32 = s0 + (tc & 32);
        const int p0 = ((tc & 8) << 1) + ((tc & 16) >> 2);
        const size_t rowoff =
            ((size_t)(b * HEADS + h) * HDIM + d) * SEQ;
        *(uint2*)&Vt[rowoff + base32 + p0] = *(const uint2*)&tmp[0];
        *(uint2*)&Vt[rowoff + base32 + p0 + 8] = *(const uint2*)&tmp[4];
    }
}

// ------- GEMM: C[M][N] = (A[M][K] @ Bt[N][K]^T + bias) * scale -------------
// 2-PHASE double-buffered staging (T3-minimum): stage tile k+1 BEFORE
// computing tile k; ONE barrier per K-step. The end-of-step barrier drains
// lgkm (reads of the buffer about to be overwritten) and vmcnt (DMA of the
// buffer about to be read) -- DMA latency hides under compute instead of
// sitting serially in every step (old form: 2 barriers, zero overlap,
// ~300 TF at K=1024). Optional cnt: early-exit beyond padded active rows.
template <bool OUT_BF16>
__global__ __launch_bounds__(256, 2) void gemm_bt(
    const u16* __restrict__ A, const u16* __restrict__ Bt,
    const float* __restrict__ bias, void* __restrict__ C,
    int M, int N, int K, float scale, const int* __restrict__ cnt) {
    __shared__ __align__(16) u16 As[2][128 * 32];   // 16 KB
    __shared__ __align__(16) u16 Bs[2][128 * 32];   // 16 KB -> 32 KB total
    const int m0 = blockIdx.y * 128, n0 = blockIdx.x * 128;
    if (cnt) {
        const int bb = m0 >> 11;
        const int cp = (cnt[bb] + 127) & ~127;
        if ((m0 & (SEQ - 1)) >= cp) return;
    }
    const int tid = threadIdx.x;
    const int w = tid >> 6, l = tid & 63;
    const int quad = l >> 4, l16 = l & 15;
    const int wm = (w >> 1) * 64, wn = (w & 1) * 64;

    auto stage = [&](int buf, int k0) {
#pragma unroll
        for (int i = 0; i < 2; ++i) {
            int c = (w * 2 + i) * 64 + l;            // lds chunk, lane-contig
            int r = c >> 2;
            int sc = (c & 3) ^ ((r >> 1) & 3);       // global chunk (swizzle)
            GLDS16(A + (size_t)(m0 + r) * K + k0 + sc * 8, &As[buf][c * 8]);
            GLDS16(Bt + (size_t)(n0 + r) * K + k0 + sc * 8, &Bs[buf][c * 8]);
        }
    };

    f32x4 acc[4][4];
#pragma unroll
    for (int i = 0; i < 4; ++i)
#pragma unroll
        for (int j = 0; j < 4; ++j) acc[i][j] = (f32x4){0.f, 0.f, 0.f, 0.f};

    stage(0, 0);
    __syncthreads();  // tile 0 visible

    int cur = 0;
    for (int k0 = 0; k0 < K; k0 += 32, cur ^= 1) {
        if (k0 + 32 < K) stage(cur ^ 1, k0 + 32);  // async prefetch k+1
        bf16x8 af[4], bfr[4];
#pragma unroll
        for (int mt = 0; mt < 4; ++mt) {
            int ra = wm + mt * 16 + l16;
            af[mt] = *(const bf16x8*)&As[cur][ra * 32 +
                                             ((quad ^ ((ra >> 1) & 3)) * 8)];
        }
#pragma unroll
        for (int nt = 0; nt < 4; ++nt) {
            int rb = wn + nt * 16 + l16;
            bfr[nt] = *(const bf16x8*)&Bs[cur][rb * 32 +
                                              ((quad ^ ((rb >> 1) & 3)) * 8)];
        }
#pragma unroll
        for (int mt = 0; mt < 4; ++mt)
#pragma unroll
            for (int nt = 0; nt < 4; ++nt)
                acc[mt][nt] = mfma16(af[mt], bfr[nt], acc[mt][nt]);
        __syncthreads();  // drains own ds_reads + next-tile DMA, then syncs
    }

#pragma unroll
    for (int mt = 0; mt < 4; ++mt) {
#pragma unroll
        for (int nt = 0; nt < 4; ++nt) {
            int col = n0 + wn + nt * 16 + l16;
            float bv = bias[col];
#pragma unroll
            for (int r = 0; r < 4; ++r) {
                int row = m0 + wm + mt * 16 + quad * 4 + r;
                float v = (acc[mt][nt][r] + bv) * scale;
                if (OUT_BF16)
                    ((u16*)C)[(size_t)row * N + col] = f2bf(v);
                else
                    ((float*)C)[(size_t)row * N + col] = v;
            }
        }
    }
}

// ------ flash attention over COMPACTED keys: Q-tile 128, S^T scores -------
// Round-2 structure (best measured: 58.1us): K AND V DMA-staged to LDS,
// double-buffered, 64 KB, 256 threads. Q pre-scaled by 1/sqrt(d)*log2(e)
// in its GEMM epilogue -> exp2(s) direct; last key tile's pads masked by
// register compare vs cnt; row-sum l on the MFMA pipe (all-ones A frag).
// V-direct variants (r5-r7: 86-94us) and 8-wave blocks (r8: 61us) both
// measured worse. launch_bounds(256,2): arg2=4 forced VGPR=64 + spill (r4).
__global__ __launch_bounds__(256, 2) void attn_kernel(
    const u16* __restrict__ Qp, const u16* __restrict__ Kp,
    const u16* __restrict__ Vt, const int* __restrict__ cnt,
    u16* __restrict__ attnb) {
    __shared__ __align__(16) u16 Ks[2][128 * 64];    // 32 KB
    __shared__ __align__(16) u16 Vts[2][64 * 128];   // 32 KB -> 64 KB total

    const int tid = threadIdx.x;
    const int w = tid >> 6, l = tid & 63;
    const int quad = l >> 4, l16 = l & 15;

    const int nqb = SEQ / 128;  // 16
    const int qb = blockIdx.x % nqb;
    const int bh = blockIdx.x / nqb;
    const int b = bh / HEADS, h = bh % HEADS;
    const int q0 = qb * 128;
    const size_t head_off = (size_t)b * SEQ * EMB + (size_t)h * HDIM;
    const size_t vt_off = (size_t)bh * HDIM * SEQ;

    const int cn = cnt[b];
    const int ntile = ((cn + 127) & ~127) >> 7;  // >=1 (mask has actives)

    auto stageKV = [&](int buf, int t) {
#pragma unroll
        for (int i = 0; i < 4; ++i) {
            int c = (w * 4 + i) * 64 + l;
            int r = c >> 3;
            int sc = (c & 7) ^ (r & 7);
            GLDS16(Kp + head_off + (size_t)(t * 128 + r) * EMB + sc * 8,
                   &Ks[buf][c * 8]);
        }
#pragma unroll
        for (int i = 0; i < 4; ++i) {
            int c = (w * 4 + i) * 64 + l;
            int r = c >> 4;
            int sc = (c & 15) ^ (r & 15);
            GLDS16(Vt + vt_off + (size_t)r * SEQ + t * 128 + sc * 8,
                   &Vts[buf][c * 8]);
        }
    };

    // Q fragments direct global->VGPR (one-time)
    bf16x8 bq[2][2];
#pragma unroll
    for (int g = 0; g < 2; ++g) {
        const u16* qrow =
            Qp + head_off + (size_t)(q0 + w * 32 + g * 16 + l16) * EMB;
        bq[g][0] = *(const bf16x8*)(qrow + quad * 8);
        bq[g][1] = *(const bf16x8*)(qrow + 32 + quad * 8);
    }

    // all-ones bf16 A fragment for row-sum MFMA
    bf16x8 ones;
#pragma unroll
    for (int e = 0; e < 8; ++e) ones[e] = (short)0x3f80;

    // prefetch tile 0
    stageKV(0, 0);
    __syncthreads();  // KV(0) visible

    f32x4 OA[4], OB[4];
#pragma unroll
    for (int i = 0; i < 4; ++i) {
        OA[i] = (f32x4){0.f, 0.f, 0.f, 0.f};
        OB[i] = (f32x4){0.f, 0.f, 0.f, 0.f};
    }
    f32x4 LA = (f32x4){0.f, 0.f, 0.f, 0.f};
    f32x4 LB = (f32x4){0.f, 0.f, 0.f, 0.f};

    auto tilebody = [&](int t, bool last) {
        const int cur = t & 1;
        if (!last) stageKV(cur ^ 1, t + 1);  // async prefetch
        const u16* ksb = Ks[cur];
        const u16* vsb = Vts[cur];

        // S^T + exp + pack, both q groups sharing K fragments
        uint32_t pk[2][8][2];
#pragma unroll
        for (int nt = 0; nt < 8; ++nt) {
            int rk = nt * 16 + l16;
            bf16x8 ka0 =
                *(const bf16x8*)&ksb[rk * 64 + ((quad ^ (rk & 7)) * 8)];
            bf16x8 ka1 =
                *(const bf16x8*)&ksb[rk * 64 + (((quad + 4) ^ (rk & 7)) * 8)];
#pragma unroll
            for (int g = 0; g < 2; ++g) {
                f32x4 s = (f32x4){0.f, 0.f, 0.f, 0.f};
                s = mfma16(ka0, bq[g][0], s);  // A=K, B=Q -> S^T
                s = mfma16(ka1, bq[g][1], s);
                f32x4 p;
                if (last) {
                    const int kb = t * 128 + nt * 16 + quad * 4;
#pragma unroll
                    for (int r = 0; r < 4; ++r)
                        p[r] = __builtin_amdgcn_exp2f(
                            (kb + r < cn) ? s[r] : -30000.f);
                } else {
#pragma unroll
                    for (int r = 0; r < 4; ++r)
                        p[r] = __builtin_amdgcn_exp2f(s[r]);
                }
                pk[g][nt][0] = pkbf(p[0], p[1]);
                pk[g][nt][1] = pkbf(p[2], p[3]);
            }
        }

        // O^T += V^T·P^T, V fragments shared across both q groups;
        // l += 1^T·P^T on the MFMA pipe
#pragma unroll
        for (int i = 0; i < 4; ++i) {
            union { bf16x8 v; uint32_t u[4]; } bpA, bpB;
            bpA.u[0] = pk[0][2 * i][0];
            bpA.u[1] = pk[0][2 * i][1];
            bpA.u[2] = pk[0][2 * i + 1][0];
            bpA.u[3] = pk[0][2 * i + 1][1];
            bpB.u[0] = pk[1][2 * i][0];
            bpB.u[1] = pk[1][2 * i][1];
            bpB.u[2] = pk[1][2 * i + 1][0];
            bpB.u[3] = pk[1][2 * i + 1][1];
            LA = mfma16(ones, bpA.v, LA);
            LB = mfma16(ones, bpB.v, LB);
#pragma unroll
            for (int dt = 0; dt < 4; ++dt) {
                int vd = dt * 16 + l16;
                bf16x8 ap = *(const bf16x8*)&vsb[vd * 128 +
                                                 (((4 * i + quad) ^ (vd & 15)) *
                                                  8)];
                OA[dt] = mfma16(ap, bpA.v, OA[dt]);
                OB[dt] = mfma16(ap, bpB.v, OB[dt]);
            }
        }

        __syncthreads();  // drains own DMA+ds_reads, then syncs (dbuf safety)
    };

    for (int t = 0; t < ntile - 1; ++t) tilebody(t, false);
    tilebody(ntile - 1, true);

    // epilogue: O[q][d] = O^T[d][q]/l; lane: q=l16, d=dt*16+quad*4+r
    // LA/LB rows are all equal (A=ones), so l = LA[0]/LB[0].
#pragma unroll
    for (int g = 0; g < 2; ++g) {
        float inv = 1.0f / (g == 0 ? LA[0] : LB[0]);
        const f32x4* O = (g == 0) ? OA : OB;
        const int orow = q0 + w * 32 + g * 16 + l16;
#pragma unroll
        for (int dt = 0; dt < 4; ++dt) {
            ushort4 o;
            o.x = f2bf(O[dt][0] * inv);
            o.y = f2bf(O[dt][1] * inv);
            o.z = f2bf(O[dt][2] * inv);
            o.w = f2bf(O[dt][3] * inv);
            *(uint2*)&attnb[head_off + (size_t)orow * EMB + dt * 16 +
                            quad * 4] = *(uint2*)&o;
        }
    }
}

extern "C" void kernel_launch(void* const* d_in, const int* in_sizes, int n_in,
                              void* d_out, int out_size, void* d_ws,
                              size_t ws_size, hipStream_t stream) {
    const float* query = (const float*)d_in[0];
    const float* key = (const float*)d_in[1];
    const float* value = (const float*)d_in[2];
    const int* mask = (const int*)d_in[3];
    const float* Wq = (const float*)d_in[4];
    const float* bq = (const float*)d_in[5];
    const float* Wk = (const float*)d_in[6];
    const float* bk = (const float*)d_in[7];
    const float* Wv = (const float*)d_in[8];
    const float* bv = (const float*)d_in[9];
    const float* Wo = (const float*)d_in[10];
    const float* bo = (const float*)d_in[11];

    char* ws = (char*)d_ws;
    const size_t MB = 1ull << 20;
    u16* xq = (u16*)(ws + 0 * MB);     // 16 MB; dead after Q-GEMM -> reused as Vt
    u16* xk = (u16*)(ws + 16 * MB);    // compacted key rows (bf16)
    u16* xv = (u16*)(ws + 32 * MB);    // compacted value rows (bf16)
    u16* Wqt = (u16*)(ws + 48 * MB);   // 2 MB each
    u16* Wkt = (u16*)(ws + 50 * MB);
    u16* Wvt = (u16*)(ws + 52 * MB);
    u16* Wot = (u16*)(ws + 54 * MB);
    u16* Qp = (u16*)(ws + 56 * MB);
    u16* Kp = (u16*)(ws + 72 * MB);
    u16* Vp = (u16*)(ws + 88 * MB);
    u16* attnb = (u16*)(ws + 104 * MB);  // total 120 MB
    u16* Vt = xq;                        // Vt[b][h][d][s-permuted], 16 MB

    // compaction scratch lives in d_out (fully overwritten by O-GEMM later)
    int* cnt = (int*)d_out;                      // 4 ints
    int* idx = (int*)d_out + 64;                 // MTOT ints

    mask_compact<<<BATCH, 256, 0, stream>>>(mask, cnt, idx);

    const int n4 = MTOT * EMB / 4;
    cast_f32_bf16<<<(n4 + 255) / 256, 256, 0, stream>>>(query, xq, n4);
    gather_cast<<<MTOT, 256, 0, stream>>>(key, idx, cnt, xk);
    gather_cast<<<MTOT, 256, 0, stream>>>(value, idx, cnt, xv);

    dim3 tgrid(EMB / 64, EMB / 64);
    transpose_cast<<<tgrid, 256, 0, stream>>>(Wq, Wqt);
    transpose_cast<<<tgrid, 256, 0, stream>>>(Wk, Wkt);
    transpose_cast<<<tgrid, 256, 0, stream>>>(Wv, Wvt);
    transpose_cast<<<tgrid, 256, 0, stream>>>(Wo, Wot);

    const float c2 = 0.125f * 1.44269504f;  // 1/sqrt(64) * log2(e)
    dim3 ggrid(EMB / 128, MTOT / 128);  // (8, 64)
    gemm_bt<true><<<ggrid, 256, 0, stream>>>(xq, Wqt, bq, Qp, MTOT, EMB, EMB,
                                             c2, nullptr);
    gemm_bt<true><<<ggrid, 256, 0, stream>>>(xk, Wkt, bk, Kp, MTOT, EMB, EMB,
                                             1.0f, cnt);
    gemm_bt<true><<<ggrid, 256, 0, stream>>>(xv, Wvt, bv, Vp, MTOT, EMB, EMB,
                                             1.0f, cnt);

    // V^T once per element, PV-permuted key order (compacted key space)
    transpose_v<<<dim3(HEADS, MTOT / 64), 256, 0, stream>>>(Vp, Vt, cnt);

    attn_kernel<<<BATCH * HEADS * (SEQ / 128), 256, 0, stream>>>(Qp, Kp, Vt,
                                                                 cnt, attnb);

    gemm_bt<false><<<ggrid, 256, 0, stream>>>(attnb, Wot, bo, d_out, MTOT, EMB,
                                              EMB, 1.0f, nullptr);
}

// Round 10
// 309.781 us; speedup vs baseline: 1.1944x; 1.1040x over previous
//
#include <hip/hip_runtime.h>
#include <hip/hip_bf16.h>
#include <stdint.h>

#define EMB 1024
#define HEADS 16
#define HDIM 64
#define BATCH 4
#define SEQ 2048
#define MTOT (BATCH * SEQ) /* 8192 */

typedef unsigned short u16;
typedef __attribute__((ext_vector_type(8))) short bf16x8;
typedef __attribute__((ext_vector_type(4))) float f32x4;

__device__ inline u16 f2bf(float f) {
    uint32_t u = __builtin_bit_cast(uint32_t, f);
    u += 0x7fffu + ((u >> 16) & 1u);  // RNE; inputs are finite
    return (u16)(u >> 16);
}

// pack 2 f32 -> 2 bf16 via compiler intrinsic (RNE; a in low half)
__device__ inline uint32_t pkbf(float a, float b) {
    __hip_bfloat162 h = __float22bfloat162_rn(make_float2(a, b));
    uint32_t r;
    __builtin_memcpy(&r, &h, 4);
    return r;
}

__device__ inline f32x4 mfma16(bf16x8 a, bf16x8 b, f32x4 c) {
    return __builtin_amdgcn_mfma_f32_16x16x32_bf16(a, b, c, 0, 0, 0);
}

#define GLDS16(gp, lp)                                                        \
    __builtin_amdgcn_global_load_lds(                                         \
        (const __attribute__((address_space(1))) void*)(gp),                  \
        (__attribute__((address_space(3))) void*)(lp), 16, 0, 0)

// ------ mask compaction: per batch, list of active key positions ----------
// cnt[b] = #active; idx[b][j] = source row of compacted key j (j < cnt).
__global__ void mask_compact(const int* __restrict__ mask,
                             int* __restrict__ cnt, int* __restrict__ idx) {
    __shared__ int ps[256];
    const int b = blockIdx.x, tid = threadIdx.x;
    const int* mp = mask + (size_t)b * SEQ;
    int m[8], s = 0;
#pragma unroll
    for (int e = 0; e < 8; ++e) {
        m[e] = mp[tid * 8 + e] ? 1 : 0;
        s += m[e];
    }
    ps[tid] = s;
    __syncthreads();
    for (int off = 1; off < 256; off <<= 1) {
        int v = (tid >= off) ? ps[tid - off] : 0;
        __syncthreads();
        if (tid >= off) ps[tid] += v;
        __syncthreads();
    }
    const int total = ps[255];
    int r = ps[tid] - s;  // exclusive prefix
#pragma unroll
    for (int e = 0; e < 8; ++e)
        if (m[e]) idx[b * SEQ + r++] = tid * 8 + e;
    if (tid == 0) cnt[b] = total;
}

// ------ fused input prep: z=0 cast query; z=1/2 gather+cast key/value -----
// gather dst row (b,j): j < cnt -> src row idx[b][j]; cnt<=j<cp -> zeros;
// j >= cp untouched (never read downstream).
__global__ void prep_cast(const float* __restrict__ query,
                          const float* __restrict__ key,
                          const float* __restrict__ value,
                          const int* __restrict__ idx,
                          const int* __restrict__ cnt, u16* __restrict__ xq,
                          u16* __restrict__ xk, u16* __restrict__ xv) {
    const int z = blockIdx.y;
    const int row = blockIdx.x;  // 0..MTOT-1
    const int c4 = threadIdx.x;  // 0..255 = EMB/4
    if (z == 0) {
        float4 v = ((const float4*)(query + (size_t)row * EMB))[c4];
        ushort4 o;
        o.x = f2bf(v.x); o.y = f2bf(v.y); o.z = f2bf(v.z); o.w = f2bf(v.w);
        ((ushort4*)(xq + (size_t)row * EMB))[c4] = o;
        return;
    }
    const int b = row >> 11, j = row & (SEQ - 1);
    const int cn = cnt[b];
    const int cp = (cn + 127) & ~127;
    if (j >= cp) return;
    const float* src = (z == 1) ? key : value;
    u16* dst = (z == 1) ? xk : xv;
    float4 v = {0.f, 0.f, 0.f, 0.f};
    if (j < cn) {
        const int srow = idx[b * SEQ + j];
        v = ((const float4*)(src + (size_t)(b * SEQ + srow) * EMB))[c4];
    }
    ushort4 o;
    o.x = f2bf(v.x); o.y = f2bf(v.y); o.z = f2bf(v.z); o.w = f2bf(v.w);
    ((ushort4*)(dst + (size_t)row * EMB))[c4] = o;
}

// ------ fused transpose+cast of all 4 weights: Wt[n][k] = W[k][n] ---------
__global__ void transpose_cast4(const float* __restrict__ Wq,
                                const float* __restrict__ Wk,
                                const float* __restrict__ Wv,
                                const float* __restrict__ Wo,
                                u16* __restrict__ Wqt, u16* __restrict__ Wkt,
                                u16* __restrict__ Wvt, u16* __restrict__ Wot) {
    __shared__ u16 T[64][65];
    const int z = blockIdx.z;
    const float* W = z == 0 ? Wq : (z == 1 ? Wk : (z == 2 ? Wv : Wo));
    u16* Wt = z == 0 ? Wqt : (z == 1 ? Wkt : (z == 2 ? Wvt : Wot));
    const int kb = blockIdx.y * 64, nb = blockIdx.x * 64;
    const int tr = threadIdx.x >> 4;         // 0..15
    const int tc = (threadIdx.x & 15) * 4;   // 0..60
#pragma unroll
    for (int j = 0; j < 4; ++j) {
        int r = tr + j * 16;
        float4 v = *(const float4*)&W[(size_t)(kb + r) * EMB + nb + tc];
        T[tc + 0][r] = f2bf(v.x);
        T[tc + 1][r] = f2bf(v.y);
        T[tc + 2][r] = f2bf(v.z);
        T[tc + 3][r] = f2bf(v.w);
    }
    __syncthreads();
#pragma unroll
    for (int j = 0; j < 4; ++j) {
        int rr = tr + j * 16;
        ushort4 o;
        o.x = T[rr][tc]; o.y = T[rr][tc + 1];
        o.z = T[rr][tc + 2]; o.w = T[rr][tc + 3];
        *(ushort4*)&Wt[(size_t)(nb + rr) * EMB + kb + tc] = o;
    }
}

// ------ fused Q/K/V projection GEMM (z selects), 2-phase dbuf staging -----
// z=0: Qp = (xq@Wqt^T + bq) * c2 (softmax scale folded)      [bf16 rows]
// z=1: Kp = xk@Wkt^T + bk   (cnt early-exit)                 [bf16 rows]
// z=2: Vt = PV-permuted transpose of (xv@Wvt^T + bv) written DIRECTLY:
//      Vt[(b*16+h)*64+d][ (s&~31) + perm(s&31) ], perm(s) =
//      ((s&15)>>2)*8 + (s&3) + 4*((s>>4)&1) -- replaces the separate
//      transpose_v kernel (saves 32 MB traffic + a launch). The 4 acc rows
//      (s aligned to 4) land in 4 consecutive permuted slots -> uint2 store.
__global__ __launch_bounds__(256, 2) void gemm_qkv(
    const u16* __restrict__ xq, const u16* __restrict__ xk,
    const u16* __restrict__ xv, const u16* __restrict__ Wqt,
    const u16* __restrict__ Wkt, const u16* __restrict__ Wvt,
    const float* __restrict__ bq, const float* __restrict__ bk,
    const float* __restrict__ bv, u16* __restrict__ Qp, u16* __restrict__ Kp,
    u16* __restrict__ Vt, const int* __restrict__ cnt, float c2) {
    __shared__ __align__(16) u16 As[2][128 * 32];
    __shared__ __align__(16) u16 Bs[2][128 * 32];
    const int z = blockIdx.z;
    const int m0 = blockIdx.y * 128, n0 = blockIdx.x * 128;
    const int bb = m0 >> 11;
    if (z) {
        const int cp = (cnt[bb] + 127) & ~127;
        if ((m0 & (SEQ - 1)) >= cp) return;
    }
    const u16* A = z == 0 ? xq : (z == 1 ? xk : xv);
    const u16* Bt = z == 0 ? Wqt : (z == 1 ? Wkt : Wvt);
    const float* bias = z == 0 ? bq : (z == 1 ? bk : bv);

    const int tid = threadIdx.x;
    const int w = tid >> 6, l = tid & 63;
    const int quad = l >> 4, l16 = l & 15;
    const int wm = (w >> 1) * 64, wn = (w & 1) * 64;

    auto stage = [&](int buf, int k0) {
#pragma unroll
        for (int i = 0; i < 2; ++i) {
            int c = (w * 2 + i) * 64 + l;            // lds chunk, lane-contig
            int r = c >> 2;
            int sc = (c & 3) ^ ((r >> 1) & 3);       // global chunk (swizzle)
            GLDS16(A + (size_t)(m0 + r) * EMB + k0 + sc * 8, &As[buf][c * 8]);
            GLDS16(Bt + (size_t)(n0 + r) * EMB + k0 + sc * 8, &Bs[buf][c * 8]);
        }
    };

    f32x4 acc[4][4];
#pragma unroll
    for (int i = 0; i < 4; ++i)
#pragma unroll
        for (int j = 0; j < 4; ++j) acc[i][j] = (f32x4){0.f, 0.f, 0.f, 0.f};

    stage(0, 0);
    __syncthreads();  // tile 0 visible

    int cur = 0;
    for (int k0 = 0; k0 < EMB; k0 += 32, cur ^= 1) {
        if (k0 + 32 < EMB) stage(cur ^ 1, k0 + 32);  // async prefetch k+1
        bf16x8 af[4], bfr[4];
#pragma unroll
        for (int mt = 0; mt < 4; ++mt) {
            int ra = wm + mt * 16 + l16;
            af[mt] = *(const bf16x8*)&As[cur][ra * 32 +
                                             ((quad ^ ((ra >> 1) & 3)) * 8)];
        }
#pragma unroll
        for (int nt = 0; nt < 4; ++nt) {
            int rb = wn + nt * 16 + l16;
            bfr[nt] = *(const bf16x8*)&Bs[cur][rb * 32 +
                                              ((quad ^ ((rb >> 1) & 3)) * 8)];
        }
#pragma unroll
        for (int mt = 0; mt < 4; ++mt)
#pragma unroll
            for (int nt = 0; nt < 4; ++nt)
                acc[mt][nt] = mfma16(af[mt], bfr[nt], acc[mt][nt]);
        __syncthreads();  // drains own ds_reads + next-tile DMA, then syncs
    }

    if (z < 2) {
        u16* C = (z == 0) ? Qp : Kp;
        const float scale = (z == 0) ? c2 : 1.0f;
#pragma unroll
        for (int mt = 0; mt < 4; ++mt) {
#pragma unroll
            for (int nt = 0; nt < 4; ++nt) {
                int col = n0 + wn + nt * 16 + l16;
                float bv_ = bias[col];
#pragma unroll
                for (int r = 0; r < 4; ++r) {
                    int row = m0 + wm + mt * 16 + quad * 4 + r;
                    C[(size_t)row * EMB + col] =
                        f2bf((acc[mt][nt][r] + bv_) * scale);
                }
            }
        }
    } else {
#pragma unroll
        for (int mt = 0; mt < 4; ++mt) {
            const int srow = (m0 & (SEQ - 1)) + wm + mt * 16 + quad * 4;
            const int grp = srow & ~31;
            const int perm = ((srow & 15) >> 2) * 8 + ((srow >> 4) & 1) * 4;
#pragma unroll
            for (int nt = 0; nt < 4; ++nt) {
                int col = n0 + wn + nt * 16 + l16;
                int h = col >> 6, d = col & 63;
                float bv_ = bias[col];
                ushort4 o;
                o.x = f2bf(acc[mt][nt][0] + bv_);
                o.y = f2bf(acc[mt][nt][1] + bv_);
                o.z = f2bf(acc[mt][nt][2] + bv_);
                o.w = f2bf(acc[mt][nt][3] + bv_);
                *(uint2*)&Vt[((size_t)(bb * HEADS + h) * HDIM + d) * SEQ +
                             grp + perm] = *(uint2*)&o;
            }
        }
    }
}

// ------- O-GEMM: C[M][N] = A[M][K] @ Bt[N][K]^T + bias (f32 out) ----------
// 2-phase double-buffered staging, one barrier per K-step.
__global__ __launch_bounds__(256, 2) void gemm_bt_f32(
    const u16* __restrict__ A, const u16* __restrict__ Bt,
    const float* __restrict__ bias, float* __restrict__ C, int K) {
    __shared__ __align__(16) u16 As[2][128 * 32];
    __shared__ __align__(16) u16 Bs[2][128 * 32];
    const int m0 = blockIdx.y * 128, n0 = blockIdx.x * 128;
    const int tid = threadIdx.x;
    const int w = tid >> 6, l = tid & 63;
    const int quad = l >> 4, l16 = l & 15;
    const int wm = (w >> 1) * 64, wn = (w & 1) * 64;

    auto stage = [&](int buf, int k0) {
#pragma unroll
        for (int i = 0; i < 2; ++i) {
            int c = (w * 2 + i) * 64 + l;
            int r = c >> 2;
            int sc = (c & 3) ^ ((r >> 1) & 3);
            GLDS16(A + (size_t)(m0 + r) * K + k0 + sc * 8, &As[buf][c * 8]);
            GLDS16(Bt + (size_t)(n0 + r) * K + k0 + sc * 8, &Bs[buf][c * 8]);
        }
    };

    f32x4 acc[4][4];
#pragma unroll
    for (int i = 0; i < 4; ++i)
#pragma unroll
        for (int j = 0; j < 4; ++j) acc[i][j] = (f32x4){0.f, 0.f, 0.f, 0.f};

    stage(0, 0);
    __syncthreads();

    int cur = 0;
    for (int k0 = 0; k0 < K; k0 += 32, cur ^= 1) {
        if (k0 + 32 < K) stage(cur ^ 1, k0 + 32);
        bf16x8 af[4], bfr[4];
#pragma unroll
        for (int mt = 0; mt < 4; ++mt) {
            int ra = wm + mt * 16 + l16;
            af[mt] = *(const bf16x8*)&As[cur][ra * 32 +
                                             ((quad ^ ((ra >> 1) & 3)) * 8)];
        }
#pragma unroll
        for (int nt = 0; nt < 4; ++nt) {
            int rb = wn + nt * 16 + l16;
            bfr[nt] = *(const bf16x8*)&Bs[cur][rb * 32 +
                                              ((quad ^ ((rb >> 1) & 3)) * 8)];
        }
#pragma unroll
        for (int mt = 0; mt < 4; ++mt)
#pragma unroll
            for (int nt = 0; nt < 4; ++nt)
                acc[mt][nt] = mfma16(af[mt], bfr[nt], acc[mt][nt]);
        __syncthreads();
    }

#pragma unroll
    for (int mt = 0; mt < 4; ++mt) {
#pragma unroll
        for (int nt = 0; nt < 4; ++nt) {
            int col = n0 + wn + nt * 16 + l16;
            float bv_ = bias[col];
#pragma unroll
            for (int r = 0; r < 4; ++r) {
                int row = m0 + wm + mt * 16 + quad * 4 + r;
                C[(size_t)row * EMB + col] = acc[mt][nt][r] + bv_;
            }
        }
    }
}

// ------ flash attention over COMPACTED keys: Q-tile 128, S^T scores -------
// Best measured structure (r2/r9: 58-60us): K AND V DMA-staged to LDS,
// double-buffered, 64 KB, 256 threads. Q pre-scaled by 1/sqrt(d)*log2(e)
// in its GEMM epilogue -> exp2(s) direct; last key tile's pads masked by
// register compare vs cnt; row-sum l on the MFMA pipe (all-ones A frag).
// V-direct variants (r5-r7: 86-94us) and 8-wave blocks (r8: 61us) measured
// worse. launch_bounds(256,2): arg2=4 forced VGPR=64 + spill (r4).
__global__ __launch_bounds__(256, 2) void attn_kernel(
    const u16* __restrict__ Qp, const u16* __restrict__ Kp,
    const u16* __restrict__ Vt, const int* __restrict__ cnt,
    u16* __restrict__ attnb) {
    __shared__ __align__(16) u16 Ks[2][128 * 64];    // 32 KB
    __shared__ __align__(16) u16 Vts[2][64 * 128];   // 32 KB -> 64 KB total

    const int tid = threadIdx.x;
    const int w = tid >> 6, l = tid & 63;
    const int quad = l >> 4, l16 = l & 15;

    const int nqb = SEQ / 128;  // 16
    const int qb = blockIdx.x % nqb;
    const int bh = blockIdx.x / nqb;
    const int b = bh / HEADS, h = bh % HEADS;
    const int q0 = qb * 128;
    const size_t head_off = (size_t)b * SEQ * EMB + (size_t)h * HDIM;
    const size_t vt_off = (size_t)bh * HDIM * SEQ;

    const int cn = cnt[b];
    const int ntile = ((cn + 127) & ~127) >> 7;  // >=1 (mask has actives)

    auto stageKV = [&](int buf, int t) {
#pragma unroll
        for (int i = 0; i < 4; ++i) {
            int c = (w * 4 + i) * 64 + l;
            int r = c >> 3;
            int sc = (c & 7) ^ (r & 7);
            GLDS16(Kp + head_off + (size_t)(t * 128 + r) * EMB + sc * 8,
                   &Ks[buf][c * 8]);
        }
#pragma unroll
        for (int i = 0; i < 4; ++i) {
            int c = (w * 4 + i) * 64 + l;
            int r = c >> 4;
            int sc = (c & 15) ^ (r & 15);
            GLDS16(Vt + vt_off + (size_t)r * SEQ + t * 128 + sc * 8,
                   &Vts[buf][c * 8]);
        }
    };

    // Q fragments direct global->VGPR (one-time)
    bf16x8 bq[2][2];
#pragma unroll
    for (int g = 0; g < 2; ++g) {
        const u16* qrow =
            Qp + head_off + (size_t)(q0 + w * 32 + g * 16 + l16) * EMB;
        bq[g][0] = *(const bf16x8*)(qrow + quad * 8);
        bq[g][1] = *(const bf16x8*)(qrow + 32 + quad * 8);
    }

    // all-ones bf16 A fragment for row-sum MFMA
    bf16x8 ones;
#pragma unroll
    for (int e = 0; e < 8; ++e) ones[e] = (short)0x3f80;

    // prefetch tile 0
    stageKV(0, 0);
    __syncthreads();  // KV(0) visible

    f32x4 OA[4], OB[4];
#pragma unroll
    for (int i = 0; i < 4; ++i) {
        OA[i] = (f32x4){0.f, 0.f, 0.f, 0.f};
        OB[i] = (f32x4){0.f, 0.f, 0.f, 0.f};
    }
    f32x4 LA = (f32x4){0.f, 0.f, 0.f, 0.f};
    f32x4 LB = (f32x4){0.f, 0.f, 0.f, 0.f};

    auto tilebody = [&](int t, bool last) {
        const int cur = t & 1;
        if (!last) stageKV(cur ^ 1, t + 1);  // async prefetch
        const u16* ksb = Ks[cur];
        const u16* vsb = Vts[cur];

        // S^T + exp + pack, both q groups sharing K fragments
        uint32_t pk[2][8][2];
#pragma unroll
        for (int nt = 0; nt < 8; ++nt) {
            int rk = nt * 16 + l16;
            bf16x8 ka0 =
                *(const bf16x8*)&ksb[rk * 64 + ((quad ^ (rk & 7)) * 8)];
            bf16x8 ka1 =
                *(const bf16x8*)&ksb[rk * 64 + (((quad + 4) ^ (rk & 7)) * 8)];
#pragma unroll
            for (int g = 0; g < 2; ++g) {
                f32x4 s = (f32x4){0.f, 0.f, 0.f, 0.f};
                s = mfma16(ka0, bq[g][0], s);  // A=K, B=Q -> S^T
                s = mfma16(ka1, bq[g][1], s);
                f32x4 p;
                if (last) {
                    const int kb = t * 128 + nt * 16 + quad * 4;
#pragma unroll
                    for (int r = 0; r < 4; ++r)
                        p[r] = __builtin_amdgcn_exp2f(
                            (kb + r < cn) ? s[r] : -30000.f);
                } else {
#pragma unroll
                    for (int r = 0; r < 4; ++r)
                        p[r] = __builtin_amdgcn_exp2f(s[r]);
                }
                pk[g][nt][0] = pkbf(p[0], p[1]);
                pk[g][nt][1] = pkbf(p[2], p[3]);
            }
        }

        // O^T += V^T·P^T, V fragments shared across both q groups;
        // l += 1^T·P^T on the MFMA pipe
#pragma unroll
        for (int i = 0; i < 4; ++i) {
            union { bf16x8 v; uint32_t u[4]; } bpA, bpB;
            bpA.u[0] = pk[0][2 * i][0];
            bpA.u[1] = pk[0][2 * i][1];
            bpA.u[2] = pk[0][2 * i + 1][0];
            bpA.u[3] = pk[0][2 * i + 1][1];
            bpB.u[0] = pk[1][2 * i][0];
            bpB.u[1] = pk[1][2 * i][1];
            bpB.u[2] = pk[1][2 * i + 1][0];
            bpB.u[3] = pk[1][2 * i + 1][1];
            LA = mfma16(ones, bpA.v, LA);
            LB = mfma16(ones, bpB.v, LB);
#pragma unroll
            for (int dt = 0; dt < 4; ++dt) {
                int vd = dt * 16 + l16;
                bf16x8 ap = *(const bf16x8*)&vsb[vd * 128 +
                                                 (((4 * i + quad) ^ (vd & 15)) *
                                                  8)];
                OA[dt] = mfma16(ap, bpA.v, OA[dt]);
                OB[dt] = mfma16(ap, bpB.v, OB[dt]);
            }
        }

        __syncthreads();  // drains own DMA+ds_reads, then syncs (dbuf safety)
    };

    for (int t = 0; t < ntile - 1; ++t) tilebody(t, false);
    tilebody(ntile - 1, true);

    // epilogue: O[q][d] = O^T[d][q]/l; lane: q=l16, d=dt*16+quad*4+r
    // LA/LB rows are all equal (A=ones), so l = LA[0]/LB[0].
#pragma unroll
    for (int g = 0; g < 2; ++g) {
        float inv = 1.0f / (g == 0 ? LA[0] : LB[0]);
        const f32x4* O = (g == 0) ? OA : OB;
        const int orow = q0 + w * 32 + g * 16 + l16;
#pragma unroll
        for (int dt = 0; dt < 4; ++dt) {
            ushort4 o;
            o.x = f2bf(O[dt][0] * inv);
            o.y = f2bf(O[dt][1] * inv);
            o.z = f2bf(O[dt][2] * inv);
            o.w = f2bf(O[dt][3] * inv);
            *(uint2*)&attnb[head_off + (size_t)orow * EMB + dt * 16 +
                            quad * 4] = *(uint2*)&o;
        }
    }
}

extern "C" void kernel_launch(void* const* d_in, const int* in_sizes, int n_in,
                              void* d_out, int out_size, void* d_ws,
                              size_t ws_size, hipStream_t stream) {
    const float* query = (const float*)d_in[0];
    const float* key = (const float*)d_in[1];
    const float* value = (const float*)d_in[2];
    const int* mask = (const int*)d_in[3];
    const float* Wq = (const float*)d_in[4];
    const float* bq = (const float*)d_in[5];
    const float* Wk = (const float*)d_in[6];
    const float* bk = (const float*)d_in[7];
    const float* Wv = (const float*)d_in[8];
    const float* bv = (const float*)d_in[9];
    const float* Wo = (const float*)d_in[10];
    const float* bo = (const float*)d_in[11];

    char* ws = (char*)d_ws;
    const size_t MB = 1ull << 20;
    u16* xq = (u16*)(ws + 0 * MB);     // 16 MB compacted/cast inputs
    u16* xk = (u16*)(ws + 16 * MB);
    u16* xv = (u16*)(ws + 32 * MB);
    u16* Wqt = (u16*)(ws + 48 * MB);   // 2 MB each
    u16* Wkt = (u16*)(ws + 50 * MB);
    u16* Wvt = (u16*)(ws + 52 * MB);
    u16* Wot = (u16*)(ws + 54 * MB);
    u16* Qp = (u16*)(ws + 56 * MB);
    u16* Kp = (u16*)(ws + 72 * MB);
    u16* Vt = (u16*)(ws + 88 * MB);    // V^T, PV-permuted (written by gemm_qkv)
    u16* attnb = (u16*)(ws + 104 * MB);  // total 120 MB

    // compaction scratch lives in d_out (fully overwritten by O-GEMM later)
    int* cnt = (int*)d_out;                      // 4 ints
    int* idx = (int*)d_out + 64;                 // MTOT ints

    mask_compact<<<BATCH, 256, 0, stream>>>(mask, cnt, idx);

    prep_cast<<<dim3(MTOT, 3), 256, 0, stream>>>(query, key, value, idx, cnt,
                                                 xq, xk, xv);

    transpose_cast4<<<dim3(EMB / 64, EMB / 64, 4), 256, 0, stream>>>(
        Wq, Wk, Wv, Wo, Wqt, Wkt, Wvt, Wot);

    const float c2 = 0.125f * 1.44269504f;  // 1/sqrt(64) * log2(e)
    gemm_qkv<<<dim3(EMB / 128, MTOT / 128, 3), 256, 0, stream>>>(
        xq, xk, xv, Wqt, Wkt, Wvt, bq, bk, bv, Qp, Kp, Vt, cnt, c2);

    attn_kernel<<<BATCH * HEADS * (SEQ / 128), 256, 0, stream>>>(Qp, Kp, Vt,
                                                                 cnt, attnb);

    gemm_bt_f32<<<dim3(EMB / 128, MTOT / 128), 256, 0, stream>>>(
        attnb, Wot, bo, (float*)d_out, EMB);
}

// Round 11
// 304.997 us; speedup vs baseline: 1.2131x; 1.0157x over previous
//
#include <hip/hip_runtime.h>
#include <hip/hip_bf16.h>
#include <stdint.h>

#define EMB 1024
#define HEADS 16
#define HDIM 64
#define BATCH 4
#define SEQ 2048
#define MTOT (BATCH * SEQ) /* 8192 */

typedef unsigned short u16;
typedef __attribute__((ext_vector_type(8))) short bf16x8;
typedef __attribute__((ext_vector_type(4))) float f32x4;

__device__ inline u16 f2bf(float f) {
    uint32_t u = __builtin_bit_cast(uint32_t, f);
    u += 0x7fffu + ((u >> 16) & 1u);  // RNE; inputs are finite
    return (u16)(u >> 16);
}

// pack 2 f32 -> 2 bf16 via compiler intrinsic (RNE; a in low half)
__device__ inline uint32_t pkbf(float a, float b) {
    __hip_bfloat162 h = __float22bfloat162_rn(make_float2(a, b));
    uint32_t r;
    __builtin_memcpy(&r, &h, 4);
    return r;
}

__device__ inline f32x4 mfma16(bf16x8 a, bf16x8 b, f32x4 c) {
    return __builtin_amdgcn_mfma_f32_16x16x32_bf16(a, b, c, 0, 0, 0);
}

#define GLDS16(gp, lp)                                                        \
    __builtin_amdgcn_global_load_lds(                                         \
        (const __attribute__((address_space(1))) void*)(gp),                  \
        (__attribute__((address_space(3))) void*)(lp), 16, 0, 0)

// ------ mask compaction: per batch, list of active key positions ----------
// cnt[b] = #active; idx[b][j] = source row of compacted key j (j < cnt).
__global__ void mask_compact(const int* __restrict__ mask,
                             int* __restrict__ cnt, int* __restrict__ idx) {
    __shared__ int ps[256];
    const int b = blockIdx.x, tid = threadIdx.x;
    const int* mp = mask + (size_t)b * SEQ;
    int m[8], s = 0;
#pragma unroll
    for (int e = 0; e < 8; ++e) {
        m[e] = mp[tid * 8 + e] ? 1 : 0;
        s += m[e];
    }
    ps[tid] = s;
    __syncthreads();
    for (int off = 1; off < 256; off <<= 1) {
        int v = (tid >= off) ? ps[tid - off] : 0;
        __syncthreads();
        if (tid >= off) ps[tid] += v;
        __syncthreads();
    }
    const int total = ps[255];
    int r = ps[tid] - s;  // exclusive prefix
#pragma unroll
    for (int e = 0; e < 8; ++e)
        if (m[e]) idx[b * SEQ + r++] = tid * 8 + e;
    if (tid == 0) cnt[b] = total;
}

// ------ fused input prep: z=0 cast query; z=1/2 gather+cast key/value -----
__global__ void prep_cast(const float* __restrict__ query,
                          const float* __restrict__ key,
                          const float* __restrict__ value,
                          const int* __restrict__ idx,
                          const int* __restrict__ cnt, u16* __restrict__ xq,
                          u16* __restrict__ xk, u16* __restrict__ xv) {
    const int z = blockIdx.y;
    const int row = blockIdx.x;  // 0..MTOT-1
    const int c4 = threadIdx.x;  // 0..255 = EMB/4
    if (z == 0) {
        float4 v = ((const float4*)(query + (size_t)row * EMB))[c4];
        ushort4 o;
        o.x = f2bf(v.x); o.y = f2bf(v.y); o.z = f2bf(v.z); o.w = f2bf(v.w);
        ((ushort4*)(xq + (size_t)row * EMB))[c4] = o;
        return;
    }
    const int b = row >> 11, j = row & (SEQ - 1);
    const int cn = cnt[b];
    const int cp = (cn + 127) & ~127;
    if (j >= cp) return;
    const float* src = (z == 1) ? key : value;
    u16* dst = (z == 1) ? xk : xv;
    float4 v = {0.f, 0.f, 0.f, 0.f};
    if (j < cn) {
        const int srow = idx[b * SEQ + j];
        v = ((const float4*)(src + (size_t)(b * SEQ + srow) * EMB))[c4];
    }
    ushort4 o;
    o.x = f2bf(v.x); o.y = f2bf(v.y); o.z = f2bf(v.z); o.w = f2bf(v.w);
    ((ushort4*)(dst + (size_t)row * EMB))[c4] = o;
}

// ------ fused transpose+cast of all 4 weights: Wt[n][k] = W[k][n] ---------
__global__ void transpose_cast4(const float* __restrict__ Wq,
                                const float* __restrict__ Wk,
                                const float* __restrict__ Wv,
                                const float* __restrict__ Wo,
                                u16* __restrict__ Wqt, u16* __restrict__ Wkt,
                                u16* __restrict__ Wvt, u16* __restrict__ Wot) {
    __shared__ u16 T[64][65];
    const int z = blockIdx.z;
    const float* W = z == 0 ? Wq : (z == 1 ? Wk : (z == 2 ? Wv : Wo));
    u16* Wt = z == 0 ? Wqt : (z == 1 ? Wkt : (z == 2 ? Wvt : Wot));
    const int kb = blockIdx.y * 64, nb = blockIdx.x * 64;
    const int tr = threadIdx.x >> 4;         // 0..15
    const int tc = (threadIdx.x & 15) * 4;   // 0..60
#pragma unroll
    for (int j = 0; j < 4; ++j) {
        int r = tr + j * 16;
        float4 v = *(const float4*)&W[(size_t)(kb + r) * EMB + nb + tc];
        T[tc + 0][r] = f2bf(v.x);
        T[tc + 1][r] = f2bf(v.y);
        T[tc + 2][r] = f2bf(v.z);
        T[tc + 3][r] = f2bf(v.w);
    }
    __syncthreads();
#pragma unroll
    for (int j = 0; j < 4; ++j) {
        int rr = tr + j * 16;
        ushort4 o;
        o.x = T[rr][tc]; o.y = T[rr][tc + 1];
        o.z = T[rr][tc + 2]; o.w = T[rr][tc + 3];
        *(ushort4*)&Wt[(size_t)(nb + rr) * EMB + kb + tc] = o;
    }
}

// XCD-aware swizzle (T1): consecutive flat dispatch IDs round-robin across
// the 8 XCD L2s, so the 8 n-blocks sharing one A-panel each HBM-fetch it
// (r10 PMC: FETCH 141 MB vs ~38 ideal). Remap so each XCD gets a contiguous
// m-major chunk: A-panel fetched once per XCD, W panels L2-resident.
// Bijective for nwg % 8 == 0 (nwg = 512 here).
__device__ inline int2 swz_mn(int flat, int nwg_div8) {
    int swz = (flat & 7) * nwg_div8 + (flat >> 3);
    return make_int2((swz >> 3) * 128, (swz & 7) * 128);  // (m0, n0)
}

// ------ fused Q/K/V projection GEMM (z selects), 2-phase dbuf staging -----
// z=0: Qp = (xq@Wqt^T + bq) * c2; z=1: Kp (cnt early-exit);
// z=2: Vt = PV-permuted transpose of (xv@Wvt^T + bv) written directly.
__global__ __launch_bounds__(256, 2) void gemm_qkv(
    const u16* __restrict__ xq, const u16* __restrict__ xk,
    const u16* __restrict__ xv, const u16* __restrict__ Wqt,
    const u16* __restrict__ Wkt, const u16* __restrict__ Wvt,
    const float* __restrict__ bq, const float* __restrict__ bk,
    const float* __restrict__ bv, u16* __restrict__ Qp, u16* __restrict__ Kp,
    u16* __restrict__ Vt, const int* __restrict__ cnt, float c2) {
    __shared__ __align__(16) u16 As[2][128 * 32];
    __shared__ __align__(16) u16 Bs[2][128 * 32];
    const int z = blockIdx.z;
    const int2 mn = swz_mn(blockIdx.y * gridDim.x + blockIdx.x,
                           (gridDim.x * gridDim.y) >> 3);
    const int m0 = mn.x, n0 = mn.y;
    const int bb = m0 >> 11;
    if (z) {
        const int cp = (cnt[bb] + 127) & ~127;
        if ((m0 & (SEQ - 1)) >= cp) return;
    }
    const u16* A = z == 0 ? xq : (z == 1 ? xk : xv);
    const u16* Bt = z == 0 ? Wqt : (z == 1 ? Wkt : Wvt);
    const float* bias = z == 0 ? bq : (z == 1 ? bk : bv);

    const int tid = threadIdx.x;
    const int w = tid >> 6, l = tid & 63;
    const int quad = l >> 4, l16 = l & 15;
    const int wm = (w >> 1) * 64, wn = (w & 1) * 64;

    auto stage = [&](int buf, int k0) {
#pragma unroll
        for (int i = 0; i < 2; ++i) {
            int c = (w * 2 + i) * 64 + l;            // lds chunk, lane-contig
            int r = c >> 2;
            int sc = (c & 3) ^ ((r >> 1) & 3);       // global chunk (swizzle)
            GLDS16(A + (size_t)(m0 + r) * EMB + k0 + sc * 8, &As[buf][c * 8]);
            GLDS16(Bt + (size_t)(n0 + r) * EMB + k0 + sc * 8, &Bs[buf][c * 8]);
        }
    };

    f32x4 acc[4][4];
#pragma unroll
    for (int i = 0; i < 4; ++i)
#pragma unroll
        for (int j = 0; j < 4; ++j) acc[i][j] = (f32x4){0.f, 0.f, 0.f, 0.f};

    stage(0, 0);
    __syncthreads();  // tile 0 visible

    int cur = 0;
    for (int k0 = 0; k0 < EMB; k0 += 32, cur ^= 1) {
        if (k0 + 32 < EMB) stage(cur ^ 1, k0 + 32);  // async prefetch k+1
        bf16x8 af[4], bfr[4];
#pragma unroll
        for (int mt = 0; mt < 4; ++mt) {
            int ra = wm + mt * 16 + l16;
            af[mt] = *(const bf16x8*)&As[cur][ra * 32 +
                                             ((quad ^ ((ra >> 1) & 3)) * 8)];
        }
#pragma unroll
        for (int nt = 0; nt < 4; ++nt) {
            int rb = wn + nt * 16 + l16;
            bfr[nt] = *(const bf16x8*)&Bs[cur][rb * 32 +
                                              ((quad ^ ((rb >> 1) & 3)) * 8)];
        }
#pragma unroll
        for (int mt = 0; mt < 4; ++mt)
#pragma unroll
            for (int nt = 0; nt < 4; ++nt)
                acc[mt][nt] = mfma16(af[mt], bfr[nt], acc[mt][nt]);
        __syncthreads();  // drains own ds_reads + next-tile DMA, then syncs
    }

    if (z < 2) {
        u16* C = (z == 0) ? Qp : Kp;
        const float scale = (z == 0) ? c2 : 1.0f;
#pragma unroll
        for (int mt = 0; mt < 4; ++mt) {
#pragma unroll
            for (int nt = 0; nt < 4; ++nt) {
                int col = n0 + wn + nt * 16 + l16;
                float bv_ = bias[col];
#pragma unroll
                for (int r = 0; r < 4; ++r) {
                    int row = m0 + wm + mt * 16 + quad * 4 + r;
                    C[(size_t)row * EMB + col] =
                        f2bf((acc[mt][nt][r] + bv_) * scale);
                }
            }
        }
    } else {
#pragma unroll
        for (int mt = 0; mt < 4; ++mt) {
            const int srow = (m0 & (SEQ - 1)) + wm + mt * 16 + quad * 4;
            const int grp = srow & ~31;
            const int perm = ((srow & 15) >> 2) * 8 + ((srow >> 4) & 1) * 4;
#pragma unroll
            for (int nt = 0; nt < 4; ++nt) {
                int col = n0 + wn + nt * 16 + l16;
                int h = col >> 6, d = col & 63;
                float bv_ = bias[col];
                ushort4 o;
                o.x = f2bf(acc[mt][nt][0] + bv_);
                o.y = f2bf(acc[mt][nt][1] + bv_);
                o.z = f2bf(acc[mt][nt][2] + bv_);
                o.w = f2bf(acc[mt][nt][3] + bv_);
                *(uint2*)&Vt[((size_t)(bb * HEADS + h) * HDIM + d) * SEQ +
                             grp + perm] = *(uint2*)&o;
            }
        }
    }
}

// ------- O-GEMM: C[M][N] = A[M][K] @ Bt[N][K]^T + bias (f32 out) ----------
// 2-phase double-buffered staging + XCD swizzle.
__global__ __launch_bounds__(256, 2) void gemm_bt_f32(
    const u16* __restrict__ A, const u16* __restrict__ Bt,
    const float* __restrict__ bias, float* __restrict__ C, int K) {
    __shared__ __align__(16) u16 As[2][128 * 32];
    __shared__ __align__(16) u16 Bs[2][128 * 32];
    const int2 mn = swz_mn(blockIdx.y * gridDim.x + blockIdx.x,
                           (gridDim.x * gridDim.y) >> 3);
    const int m0 = mn.x, n0 = mn.y;
    const int tid = threadIdx.x;
    const int w = tid >> 6, l = tid & 63;
    const int quad = l >> 4, l16 = l & 15;
    const int wm = (w >> 1) * 64, wn = (w & 1) * 64;

    auto stage = [&](int buf, int k0) {
#pragma unroll
        for (int i = 0; i < 2; ++i) {
            int c = (w * 2 + i) * 64 + l;
            int r = c >> 2;
            int sc = (c & 3) ^ ((r >> 1) & 3);
            GLDS16(A + (size_t)(m0 + r) * K + k0 + sc * 8, &As[buf][c * 8]);
            GLDS16(Bt + (size_t)(n0 + r) * K + k0 + sc * 8, &Bs[buf][c * 8]);
        }
    };

    f32x4 acc[4][4];
#pragma unroll
    for (int i = 0; i < 4; ++i)
#pragma unroll
        for (int j = 0; j < 4; ++j) acc[i][j] = (f32x4){0.f, 0.f, 0.f, 0.f};

    stage(0, 0);
    __syncthreads();

    int cur = 0;
    for (int k0 = 0; k0 < K; k0 += 32, cur ^= 1) {
        if (k0 + 32 < K) stage(cur ^ 1, k0 + 32);
        bf16x8 af[4], bfr[4];
#pragma unroll
        for (int mt = 0; mt < 4; ++mt) {
            int ra = wm + mt * 16 + l16;
            af[mt] = *(const bf16x8*)&As[cur][ra * 32 +
                                             ((quad ^ ((ra >> 1) & 3)) * 8)];
        }
#pragma unroll
        for (int nt = 0; nt < 4; ++nt) {
            int rb = wn + nt * 16 + l16;
            bfr[nt] = *(const bf16x8*)&Bs[cur][rb * 32 +
                                              ((quad ^ ((rb >> 1) & 3)) * 8)];
        }
#pragma unroll
        for (int mt = 0; mt < 4; ++mt)
#pragma unroll
            for (int nt = 0; nt < 4; ++nt)
                acc[mt][nt] = mfma16(af[mt], bfr[nt], acc[mt][nt]);
        __syncthreads();
    }

#pragma unroll
    for (int mt = 0; mt < 4; ++mt) {
#pragma unroll
        for (int nt = 0; nt < 4; ++nt) {
            int col = n0 + wn + nt * 16 + l16;
            float bv_ = bias[col];
#pragma unroll
            for (int r = 0; r < 4; ++r) {
                int row = m0 + wm + mt * 16 + quad * 4 + r;
                C[(size_t)row * EMB + col] = acc[mt][nt][r] + bv_;
            }
        }
    }
}

// ------ flash attention over COMPACTED keys: Q-tile 128, S^T scores -------
// Best measured structure (r2/r9: 58-60us): K AND V DMA-staged to LDS,
// double-buffered, 64 KB, 256 threads. Q pre-scaled by 1/sqrt(d)*log2(e)
// in its GEMM epilogue -> exp2(s) direct; last key tile's pads masked by
// register compare vs cnt; row-sum l on the MFMA pipe (all-ones A frag).
__global__ __launch_bounds__(256, 2) void attn_kernel(
    const u16* __restrict__ Qp, const u16* __restrict__ Kp,
    const u16* __restrict__ Vt, const int* __restrict__ cnt,
    u16* __restrict__ attnb) {
    __shared__ __align__(16) u16 Ks[2][128 * 64];    // 32 KB
    __shared__ __align__(16) u16 Vts[2][64 * 128];   // 32 KB -> 64 KB total

    const int tid = threadIdx.x;
    const int w = tid >> 6, l = tid & 63;
    const int quad = l >> 4, l16 = l & 15;

    const int nqb = SEQ / 128;  // 16
    const int qb = blockIdx.x % nqb;
    const int bh = blockIdx.x / nqb;
    const int b = bh / HEADS, h = bh % HEADS;
    const int q0 = qb * 128;
    const size_t head_off = (size_t)b * SEQ * EMB + (size_t)h * HDIM;
    const size_t vt_off = (size_t)bh * HDIM * SEQ;

    const int cn = cnt[b];
    const int ntile = ((cn + 127) & ~127) >> 7;  // >=1 (mask has actives)

    auto stageKV = [&](int buf, int t) {
#pragma unroll
        for (int i = 0; i < 4; ++i) {
            int c = (w * 4 + i) * 64 + l;
            int r = c >> 3;
            int sc = (c & 7) ^ (r & 7);
            GLDS16(Kp + head_off + (size_t)(t * 128 + r) * EMB + sc * 8,
                   &Ks[buf][c * 8]);
        }
#pragma unroll
        for (int i = 0; i < 4; ++i) {
            int c = (w * 4 + i) * 64 + l;
            int r = c >> 4;
            int sc = (c & 15) ^ (r & 15);
            GLDS16(Vt + vt_off + (size_t)r * SEQ + t * 128 + sc * 8,
                   &Vts[buf][c * 8]);
        }
    };

    // Q fragments direct global->VGPR (one-time)
    bf16x8 bq[2][2];
#pragma unroll
    for (int g = 0; g < 2; ++g) {
        const u16* qrow =
            Qp + head_off + (size_t)(q0 + w * 32 + g * 16 + l16) * EMB;
        bq[g][0] = *(const bf16x8*)(qrow + quad * 8);
        bq[g][1] = *(const bf16x8*)(qrow + 32 + quad * 8);
    }

    // all-ones bf16 A fragment for row-sum MFMA
    bf16x8 ones;
#pragma unroll
    for (int e = 0; e < 8; ++e) ones[e] = (short)0x3f80;

    // prefetch tile 0
    stageKV(0, 0);
    __syncthreads();  // KV(0) visible

    f32x4 OA[4], OB[4];
#pragma unroll
    for (int i = 0; i < 4; ++i) {
        OA[i] = (f32x4){0.f, 0.f, 0.f, 0.f};
        OB[i] = (f32x4){0.f, 0.f, 0.f, 0.f};
    }
    f32x4 LA = (f32x4){0.f, 0.f, 0.f, 0.f};
    f32x4 LB = (f32x4){0.f, 0.f, 0.f, 0.f};

    auto tilebody = [&](int t, bool last) {
        const int cur = t & 1;
        if (!last) stageKV(cur ^ 1, t + 1);  // async prefetch
        const u16* ksb = Ks[cur];
        const u16* vsb = Vts[cur];

        // S^T + exp + pack, both q groups sharing K fragments
        uint32_t pk[2][8][2];
#pragma unroll
        for (int nt = 0; nt < 8; ++nt) {
            int rk = nt * 16 + l16;
            bf16x8 ka0 =
                *(const bf16x8*)&ksb[rk * 64 + ((quad ^ (rk & 7)) * 8)];
            bf16x8 ka1 =
                *(const bf16x8*)&ksb[rk * 64 + (((quad + 4) ^ (rk & 7)) * 8)];
#pragma unroll
            for (int g = 0; g < 2; ++g) {
                f32x4 s = (f32x4){0.f, 0.f, 0.f, 0.f};
                s = mfma16(ka0, bq[g][0], s);  // A=K, B=Q -> S^T
                s = mfma16(ka1, bq[g][1], s);
                f32x4 p;
                if (last) {
                    const int kb = t * 128 + nt * 16 + quad * 4;
#pragma unroll
                    for (int r = 0; r < 4; ++r)
                        p[r] = __builtin_amdgcn_exp2f(
                            (kb + r < cn) ? s[r] : -30000.f);
                } else {
#pragma unroll
                    for (int r = 0; r < 4; ++r)
                        p[r] = __builtin_amdgcn_exp2f(s[r]);
                }
                pk[g][nt][0] = pkbf(p[0], p[1]);
                pk[g][nt][1] = pkbf(p[2], p[3]);
            }
        }

        // O^T += V^T·P^T, V fragments shared across both q groups;
        // l += 1^T·P^T on the MFMA pipe
#pragma unroll
        for (int i = 0; i < 4; ++i) {
            union { bf16x8 v; uint32_t u[4]; } bpA, bpB;
            bpA.u[0] = pk[0][2 * i][0];
            bpA.u[1] = pk[0][2 * i][1];
            bpA.u[2] = pk[0][2 * i + 1][0];
            bpA.u[3] = pk[0][2 * i + 1][1];
            bpB.u[0] = pk[1][2 * i][0];
            bpB.u[1] = pk[1][2 * i][1];
            bpB.u[2] = pk[1][2 * i + 1][0];
            bpB.u[3] = pk[1][2 * i + 1][1];
            LA = mfma16(ones, bpA.v, LA);
            LB = mfma16(ones, bpB.v, LB);
#pragma unroll
            for (int dt = 0; dt < 4; ++dt) {
                int vd = dt * 16 + l16;
                bf16x8 ap = *(const bf16x8*)&vsb[vd * 128 +
                                                 (((4 * i + quad) ^ (vd & 15)) *
                                                  8)];
                OA[dt] = mfma16(ap, bpA.v, OA[dt]);
                OB[dt] = mfma16(ap, bpB.v, OB[dt]);
            }
        }

        __syncthreads();  // drains own DMA+ds_reads, then syncs (dbuf safety)
    };

    for (int t = 0; t < ntile - 1; ++t) tilebody(t, false);
    tilebody(ntile - 1, true);

    // epilogue: O[q][d] = O^T[d][q]/l; lane: q=l16, d=dt*16+quad*4+r
    // LA/LB rows are all equal (A=ones), so l = LA[0]/LB[0].
#pragma unroll
    for (int g = 0; g < 2; ++g) {
        float inv = 1.0f / (g == 0 ? LA[0] : LB[0]);
        const f32x4* O = (g == 0) ? OA : OB;
        const int orow = q0 + w * 32 + g * 16 + l16;
#pragma unroll
        for (int dt = 0; dt < 4; ++dt) {
            ushort4 o;
            o.x = f2bf(O[dt][0] * inv);
            o.y = f2bf(O[dt][1] * inv);
            o.z = f2bf(O[dt][2] * inv);
            o.w = f2bf(O[dt][3] * inv);
            *(uint2*)&attnb[head_off + (size_t)orow * EMB + dt * 16 +
                            quad * 4] = *(uint2*)&o;
        }
    }
}

extern "C" void kernel_launch(void* const* d_in, const int* in_sizes, int n_in,
                              void* d_out, int out_size, void* d_ws,
                              size_t ws_size, hipStream_t stream) {
    const float* query = (const float*)d_in[0];
    const float* key = (const float*)d_in[1];
    const float* value = (const float*)d_in[2];
    const int* mask = (const int*)d_in[3];
    const float* Wq = (const float*)d_in[4];
    const float* bq = (const float*)d_in[5];
    const float* Wk = (const float*)d_in[6];
    const float* bk = (const float*)d_in[7];
    const float* Wv = (const float*)d_in[8];
    const float* bv = (const float*)d_in[9];
    const float* Wo = (const float*)d_in[10];
    const float* bo = (const float*)d_in[11];

    char* ws = (char*)d_ws;
    const size_t MB = 1ull << 20;
    u16* xq = (u16*)(ws + 0 * MB);     // 16 MB compacted/cast inputs
    u16* xk = (u16*)(ws + 16 * MB);
    u16* xv = (u16*)(ws + 32 * MB);
    u16* Wqt = (u16*)(ws + 48 * MB);   // 2 MB each
    u16* Wkt = (u16*)(ws + 50 * MB);
    u16* Wvt = (u16*)(ws + 52 * MB);
    u16* Wot = (u16*)(ws + 54 * MB);
    u16* Qp = (u16*)(ws + 56 * MB);
    u16* Kp = (u16*)(ws + 72 * MB);
    u16* Vt = (u16*)(ws + 88 * MB);    // V^T, PV-permuted (written by gemm_qkv)
    u16* attnb = (u16*)(ws + 104 * MB);  // total 120 MB

    // compaction scratch lives in d_out (fully overwritten by O-GEMM later)
    int* cnt = (int*)d_out;                      // 4 ints
    int* idx = (int*)d_out + 64;                 // MTOT ints

    mask_compact<<<BATCH, 256, 0, stream>>>(mask, cnt, idx);

    prep_cast<<<dim3(MTOT, 3), 256, 0, stream>>>(query, key, value, idx, cnt,
                                                 xq, xk, xv);

    transpose_cast4<<<dim3(EMB / 64, EMB / 64, 4), 256, 0, stream>>>(
        Wq, Wk, Wv, Wo, Wqt, Wkt, Wvt, Wot);

    const float c2 = 0.125f * 1.44269504f;  // 1/sqrt(64) * log2(e)
    gemm_qkv<<<dim3(EMB / 128, MTOT / 128, 3), 256, 0, stream>>>(
        xq, xk, xv, Wqt, Wkt, Wvt, bq, bk, bv, Qp, Kp, Vt, cnt, c2);

    attn_kernel<<<BATCH * HEADS * (SEQ / 128), 256, 0, stream>>>(Qp, Kp, Vt,
                                                                 cnt, attnb);

    gemm_bt_f32<<<dim3(EMB / 128, MTOT / 128), 256, 0, stream>>>(
        attnb, Wot, bo, (float*)d_out, EMB);
}

// Round 12
// 301.382 us; speedup vs baseline: 1.2277x; 1.0120x over previous
//
#include <hip/hip_runtime.h>
#include <hip/hip_bf16.h>
#include <stdint.h>

#define EMB 1024
#define HEADS 16
#define HDIM 64
#define BATCH 4
#define SEQ 2048
#define MTOT (BATCH * SEQ) /* 8192 */

typedef unsigned short u16;
typedef __attribute__((ext_vector_type(8))) short bf16x8;
typedef __attribute__((ext_vector_type(4))) float f32x4;

__device__ inline u16 f2bf(float f) {
    uint32_t u = __builtin_bit_cast(uint32_t, f);
    u += 0x7fffu + ((u >> 16) & 1u);  // RNE; inputs are finite
    return (u16)(u >> 16);
}

// pack 2 f32 -> 2 bf16 via compiler intrinsic (RNE; a in low half)
__device__ inline uint32_t pkbf(float a, float b) {
    __hip_bfloat162 h = __float22bfloat162_rn(make_float2(a, b));
    uint32_t r;
    __builtin_memcpy(&r, &h, 4);
    return r;
}

__device__ inline f32x4 mfma16(bf16x8 a, bf16x8 b, f32x4 c) {
    return __builtin_amdgcn_mfma_f32_16x16x32_bf16(a, b, c, 0, 0, 0);
}

#define GLDS16(gp, lp)                                                        \
    __builtin_amdgcn_global_load_lds(                                         \
        (const __attribute__((address_space(1))) void*)(gp),                  \
        (__attribute__((address_space(3))) void*)(lp), 16, 0, 0)

// ------ mask compaction: per batch, list of active key positions ----------
// cnt[b] = #active; idx[b][j] = source row of compacted key j (j < cnt).
__global__ void mask_compact(const int* __restrict__ mask,
                             int* __restrict__ cnt, int* __restrict__ idx) {
    __shared__ int ps[256];
    const int b = blockIdx.x, tid = threadIdx.x;
    const int* mp = mask + (size_t)b * SEQ;
    int m[8], s = 0;
#pragma unroll
    for (int e = 0; e < 8; ++e) {
        m[e] = mp[tid * 8 + e] ? 1 : 0;
        s += m[e];
    }
    ps[tid] = s;
    __syncthreads();
    for (int off = 1; off < 256; off <<= 1) {
        int v = (tid >= off) ? ps[tid - off] : 0;
        __syncthreads();
        if (tid >= off) ps[tid] += v;
        __syncthreads();
    }
    const int total = ps[255];
    int r = ps[tid] - s;  // exclusive prefix
#pragma unroll
    for (int e = 0; e < 8; ++e)
        if (m[e]) idx[b * SEQ + r++] = tid * 8 + e;
    if (tid == 0) cnt[b] = total;
}

// ------ fused input prep: z=0 cast query; z=1/2 gather+cast key/value -----
__global__ void prep_cast(const float* __restrict__ query,
                          const float* __restrict__ key,
                          const float* __restrict__ value,
                          const int* __restrict__ idx,
                          const int* __restrict__ cnt, u16* __restrict__ xq,
                          u16* __restrict__ xk, u16* __restrict__ xv) {
    const int z = blockIdx.y;
    const int row = blockIdx.x;  // 0..MTOT-1
    const int c4 = threadIdx.x;  // 0..255 = EMB/4
    if (z == 0) {
        float4 v = ((const float4*)(query + (size_t)row * EMB))[c4];
        ushort4 o;
        o.x = f2bf(v.x); o.y = f2bf(v.y); o.z = f2bf(v.z); o.w = f2bf(v.w);
        ((ushort4*)(xq + (size_t)row * EMB))[c4] = o;
        return;
    }
    const int b = row >> 11, j = row & (SEQ - 1);
    const int cn = cnt[b];
    const int cp = (cn + 127) & ~127;
    if (j >= cp) return;
    const float* src = (z == 1) ? key : value;
    u16* dst = (z == 1) ? xk : xv;
    float4 v = {0.f, 0.f, 0.f, 0.f};
    if (j < cn) {
        const int srow = idx[b * SEQ + j];
        v = ((const float4*)(src + (size_t)(b * SEQ + srow) * EMB))[c4];
    }
    ushort4 o;
    o.x = f2bf(v.x); o.y = f2bf(v.y); o.z = f2bf(v.z); o.w = f2bf(v.w);
    ((ushort4*)(dst + (size_t)row * EMB))[c4] = o;
}

// ------ fused transpose+cast of all 4 weights: Wt[n][k] = W[k][n] ---------
__global__ void transpose_cast4(const float* __restrict__ Wq,
                                const float* __restrict__ Wk,
                                const float* __restrict__ Wv,
                                const float* __restrict__ Wo,
                                u16* __restrict__ Wqt, u16* __restrict__ Wkt,
                                u16* __restrict__ Wvt, u16* __restrict__ Wot) {
    __shared__ u16 T[64][65];
    const int z = blockIdx.z;
    const float* W = z == 0 ? Wq : (z == 1 ? Wk : (z == 2 ? Wv : Wo));
    u16* Wt = z == 0 ? Wqt : (z == 1 ? Wkt : (z == 2 ? Wvt : Wot));
    const int kb = blockIdx.y * 64, nb = blockIdx.x * 64;
    const int tr = threadIdx.x >> 4;         // 0..15
    const int tc = (threadIdx.x & 15) * 4;   // 0..60
#pragma unroll
    for (int j = 0; j < 4; ++j) {
        int r = tr + j * 16;
        float4 v = *(const float4*)&W[(size_t)(kb + r) * EMB + nb + tc];
        T[tc + 0][r] = f2bf(v.x);
        T[tc + 1][r] = f2bf(v.y);
        T[tc + 2][r] = f2bf(v.z);
        T[tc + 3][r] = f2bf(v.w);
    }
    __syncthreads();
#pragma unroll
    for (int j = 0; j < 4; ++j) {
        int rr = tr + j * 16;
        ushort4 o;
        o.x = T[rr][tc]; o.y = T[rr][tc + 1];
        o.z = T[rr][tc + 2]; o.w = T[rr][tc + 3];
        *(ushort4*)&Wt[(size_t)(nb + rr) * EMB + kb + tc] = o;
    }
}

// XCD-aware swizzle (T1): verified r11 -- FETCH 141 -> 39.8 MB (ideal).
__device__ inline int2 swz_mn(int flat, int nwg_div8) {
    int swz = (flat & 7) * nwg_div8 + (flat >> 3);
    return make_int2((swz >> 3) * 128, (swz & 7) * 128);  // (m0, n0)
}

// ------ fused Q/K/V projection GEMM, 3-buffer counted-vmcnt pipeline ------
// r11 PMC: FETCH ideal, MfmaUtil 19%, HBM 13% -> pure latency-bound. The
// __syncthreads() barrier emitted vmcnt(0), draining the very prefetch it
// was meant to overlap (T4 lesson). Now: 3 LDS buffers; stage s+2 issued
// while computing s; steady-state s_waitcnt vmcnt(8) keeps 2 stages (8
// loads) in flight ACROSS barriers. barrier2 (lgkmcnt-protected) guards
// buffer reuse at distance 3. z=0: Qp=(xq@Wqt^T+bq)*c2; z=1: Kp (cnt
// early-exit, block-uniform, before first barrier); z=2: Vt PV-permuted.
__global__ __launch_bounds__(256, 2) void gemm_qkv(
    const u16* __restrict__ xq, const u16* __restrict__ xk,
    const u16* __restrict__ xv, const u16* __restrict__ Wqt,
    const u16* __restrict__ Wkt, const u16* __restrict__ Wvt,
    const float* __restrict__ bq, const float* __restrict__ bk,
    const float* __restrict__ bv, u16* __restrict__ Qp, u16* __restrict__ Kp,
    u16* __restrict__ Vt, const int* __restrict__ cnt, float c2) {
    __shared__ __align__(16) u16 As[3][128 * 32];   // 24 KB
    __shared__ __align__(16) u16 Bs[3][128 * 32];   // 24 KB -> 48 KB total
    const int z = blockIdx.z;
    const int2 mn = swz_mn(blockIdx.y * gridDim.x + blockIdx.x,
                           (gridDim.x * gridDim.y) >> 3);
    const int m0 = mn.x, n0 = mn.y;
    const int bb = m0 >> 11;
    if (z) {
        const int cp = (cnt[bb] + 127) & ~127;
        if ((m0 & (SEQ - 1)) >= cp) return;
    }
    const u16* A = z == 0 ? xq : (z == 1 ? xk : xv);
    const u16* Bt = z == 0 ? Wqt : (z == 1 ? Wkt : Wvt);
    const float* bias = z == 0 ? bq : (z == 1 ? bk : bv);

    const int tid = threadIdx.x;
    const int w = tid >> 6, l = tid & 63;
    const int quad = l >> 4, l16 = l & 15;
    const int wm = (w >> 1) * 64, wn = (w & 1) * 64;

    auto stage = [&](int buf, int k0) {  // 4 loads/thread: A,B,A,B order
#pragma unroll
        for (int i = 0; i < 2; ++i) {
            int c = (w * 2 + i) * 64 + l;            // lds chunk, lane-contig
            int r = c >> 2;
            int sc = (c & 3) ^ ((r >> 1) & 3);       // global chunk (swizzle)
            GLDS16(A + (size_t)(m0 + r) * EMB + k0 + sc * 8, &As[buf][c * 8]);
            GLDS16(Bt + (size_t)(n0 + r) * EMB + k0 + sc * 8, &Bs[buf][c * 8]);
        }
    };

    f32x4 acc[4][4];
#pragma unroll
    for (int i = 0; i < 4; ++i)
#pragma unroll
        for (int j = 0; j < 4; ++j) acc[i][j] = (f32x4){0.f, 0.f, 0.f, 0.f};

    const int NS = EMB / 32;  // 32 K-steps
    stage(0, 0);
    stage(1, 32);

    for (int s = 0; s < NS; ++s) {
        const int cb = s % 3;
        if (s + 2 < NS) {
            stage((s + 2) % 3, (s + 2) * 32);
            // stages s+1, s+2 in flight (8 loads); oldest 4 (stage s) done
            asm volatile("s_waitcnt vmcnt(8)" ::: "memory");
        } else if (s + 1 < NS) {
            asm volatile("s_waitcnt vmcnt(4)" ::: "memory");
        } else {
            asm volatile("s_waitcnt vmcnt(0)" ::: "memory");
        }
        __builtin_amdgcn_sched_barrier(0);
        __builtin_amdgcn_s_barrier();        // buf cb ready for all waves
        __builtin_amdgcn_sched_barrier(0);

        bf16x8 af[4], bfr[4];
#pragma unroll
        for (int mt = 0; mt < 4; ++mt) {
            int ra = wm + mt * 16 + l16;
            af[mt] = *(const bf16x8*)&As[cb][ra * 32 +
                                            ((quad ^ ((ra >> 1) & 3)) * 8)];
        }
#pragma unroll
        for (int nt = 0; nt < 4; ++nt) {
            int rb = wn + nt * 16 + l16;
            bfr[nt] = *(const bf16x8*)&Bs[cb][rb * 32 +
                                             ((quad ^ ((rb >> 1) & 3)) * 8)];
        }
#pragma unroll
        for (int mt = 0; mt < 4; ++mt)
#pragma unroll
            for (int nt = 0; nt < 4; ++nt)
                acc[mt][nt] = mfma16(af[mt], bfr[nt], acc[mt][nt]);

        // all ds_reads of buf cb retired before anyone re-DMAs it (dist 3)
        asm volatile("s_waitcnt lgkmcnt(0)" ::: "memory");
        __builtin_amdgcn_sched_barrier(0);
        __builtin_amdgcn_s_barrier();
    }

    if (z < 2) {
        u16* C = (z == 0) ? Qp : Kp;
        const float scale = (z == 0) ? c2 : 1.0f;
#pragma unroll
        for (int mt = 0; mt < 4; ++mt) {
#pragma unroll
            for (int nt = 0; nt < 4; ++nt) {
                int col = n0 + wn + nt * 16 + l16;
                float bv_ = bias[col];
#pragma unroll
                for (int r = 0; r < 4; ++r) {
                    int row = m0 + wm + mt * 16 + quad * 4 + r;
                    C[(size_t)row * EMB + col] =
                        f2bf((acc[mt][nt][r] + bv_) * scale);
                }
            }
        }
    } else {
#pragma unroll
        for (int mt = 0; mt < 4; ++mt) {
            const int srow = (m0 & (SEQ - 1)) + wm + mt * 16 + quad * 4;
            const int grp = srow & ~31;
            const int perm = ((srow & 15) >> 2) * 8 + ((srow >> 4) & 1) * 4;
#pragma unroll
            for (int nt = 0; nt < 4; ++nt) {
                int col = n0 + wn + nt * 16 + l16;
                int h = col >> 6, d = col & 63;
                float bv_ = bias[col];
                ushort4 o;
                o.x = f2bf(acc[mt][nt][0] + bv_);
                o.y = f2bf(acc[mt][nt][1] + bv_);
                o.z = f2bf(acc[mt][nt][2] + bv_);
                o.w = f2bf(acc[mt][nt][3] + bv_);
                *(uint2*)&Vt[((size_t)(bb * HEADS + h) * HDIM + d) * SEQ +
                             grp + perm] = *(uint2*)&o;
            }
        }
    }
}

// ------- O-GEMM: C[M][N] = A[M][K] @ Bt[N][K]^T + bias (f32 out) ----------
// Same 3-buffer counted-vmcnt pipeline + XCD swizzle.
__global__ __launch_bounds__(256, 2) void gemm_bt_f32(
    const u16* __restrict__ A, const u16* __restrict__ Bt,
    const float* __restrict__ bias, float* __restrict__ C, int K) {
    __shared__ __align__(16) u16 As[3][128 * 32];
    __shared__ __align__(16) u16 Bs[3][128 * 32];
    const int2 mn = swz_mn(blockIdx.y * gridDim.x + blockIdx.x,
                           (gridDim.x * gridDim.y) >> 3);
    const int m0 = mn.x, n0 = mn.y;
    const int tid = threadIdx.x;
    const int w = tid >> 6, l = tid & 63;
    const int quad = l >> 4, l16 = l & 15;
    const int wm = (w >> 1) * 64, wn = (w & 1) * 64;

    auto stage = [&](int buf, int k0) {
#pragma unroll
        for (int i = 0; i < 2; ++i) {
            int c = (w * 2 + i) * 64 + l;
            int r = c >> 2;
            int sc = (c & 3) ^ ((r >> 1) & 3);
            GLDS16(A + (size_t)(m0 + r) * K + k0 + sc * 8, &As[buf][c * 8]);
            GLDS16(Bt + (size_t)(n0 + r) * K + k0 + sc * 8, &Bs[buf][c * 8]);
        }
    };

    f32x4 acc[4][4];
#pragma unroll
    for (int i = 0; i < 4; ++i)
#pragma unroll
        for (int j = 0; j < 4; ++j) acc[i][j] = (f32x4){0.f, 0.f, 0.f, 0.f};

    const int NS = K / 32;
    stage(0, 0);
    stage(1, 32);

    for (int s = 0; s < NS; ++s) {
        const int cb = s % 3;
        if (s + 2 < NS) {
            stage((s + 2) % 3, (s + 2) * 32);
            asm volatile("s_waitcnt vmcnt(8)" ::: "memory");
        } else if (s + 1 < NS) {
            asm volatile("s_waitcnt vmcnt(4)" ::: "memory");
        } else {
            asm volatile("s_waitcnt vmcnt(0)" ::: "memory");
        }
        __builtin_amdgcn_sched_barrier(0);
        __builtin_amdgcn_s_barrier();
        __builtin_amdgcn_sched_barrier(0);

        bf16x8 af[4], bfr[4];
#pragma unroll
        for (int mt = 0; mt < 4; ++mt) {
            int ra = wm + mt * 16 + l16;
            af[mt] = *(const bf16x8*)&As[cb][ra * 32 +
                                            ((quad ^ ((ra >> 1) & 3)) * 8)];
        }
#pragma unroll
        for (int nt = 0; nt < 4; ++nt) {
            int rb = wn + nt * 16 + l16;
            bfr[nt] = *(const bf16x8*)&Bs[cb][rb * 32 +
                                             ((quad ^ ((rb >> 1) & 3)) * 8)];
        }
#pragma unroll
        for (int mt = 0; mt < 4; ++mt)
#pragma unroll
            for (int nt = 0; nt < 4; ++nt)
                acc[mt][nt] = mfma16(af[mt], bfr[nt], acc[mt][nt]);

        asm volatile("s_waitcnt lgkmcnt(0)" ::: "memory");
        __builtin_amdgcn_sched_barrier(0);
        __builtin_amdgcn_s_barrier();
    }

#pragma unroll
    for (int mt = 0; mt < 4; ++mt) {
#pragma unroll
        for (int nt = 0; nt < 4; ++nt) {
            int col = n0 + wn + nt * 16 + l16;
            float bv_ = bias[col];
#pragma unroll
            for (int r = 0; r < 4; ++r) {
                int row = m0 + wm + mt * 16 + quad * 4 + r;
                C[(size_t)row * EMB + col] = acc[mt][nt][r] + bv_;
            }
        }
    }
}

// ------ flash attention over COMPACTED keys: Q-tile 128, S^T scores -------
// Best measured structure (r2/r9: 58-60us): K AND V DMA-staged to LDS,
// double-buffered, 64 KB, 256 threads. Q pre-scaled by 1/sqrt(d)*log2(e)
// in its GEMM epilogue -> exp2(s) direct; last key tile's pads masked by
// register compare vs cnt; row-sum l on the MFMA pipe (all-ones A frag).
__global__ __launch_bounds__(256, 2) void attn_kernel(
    const u16* __restrict__ Qp, const u16* __restrict__ Kp,
    const u16* __restrict__ Vt, const int* __restrict__ cnt,
    u16* __restrict__ attnb) {
    __shared__ __align__(16) u16 Ks[2][128 * 64];    // 32 KB
    __shared__ __align__(16) u16 Vts[2][64 * 128];   // 32 KB -> 64 KB total

    const int tid = threadIdx.x;
    const int w = tid >> 6, l = tid & 63;
    const int quad = l >> 4, l16 = l & 15;

    const int nqb = SEQ / 128;  // 16
    const int qb = blockIdx.x % nqb;
    const int bh = blockIdx.x / nqb;
    const int b = bh / HEADS, h = bh % HEADS;
    const int q0 = qb * 128;
    const size_t head_off = (size_t)b * SEQ * EMB + (size_t)h * HDIM;
    const size_t vt_off = (size_t)bh * HDIM * SEQ;

    const int cn = cnt[b];
    const int ntile = ((cn + 127) & ~127) >> 7;  // >=1 (mask has actives)

    auto stageKV = [&](int buf, int t) {
#pragma unroll
        for (int i = 0; i < 4; ++i) {
            int c = (w * 4 + i) * 64 + l;
            int r = c >> 3;
            int sc = (c & 7) ^ (r & 7);
            GLDS16(Kp + head_off + (size_t)(t * 128 + r) * EMB + sc * 8,
                   &Ks[buf][c * 8]);
        }
#pragma unroll
        for (int i = 0; i < 4; ++i) {
            int c = (w * 4 + i) * 64 + l;
            int r = c >> 4;
            int sc = (c & 15) ^ (r & 15);
            GLDS16(Vt + vt_off + (size_t)r * SEQ + t * 128 + sc * 8,
                   &Vts[buf][c * 8]);
        }
    };

    // Q fragments direct global->VGPR (one-time)
    bf16x8 bq[2][2];
#pragma unroll
    for (int g = 0; g < 2; ++g) {
        const u16* qrow =
            Qp + head_off + (size_t)(q0 + w * 32 + g * 16 + l16) * EMB;
        bq[g][0] = *(const bf16x8*)(qrow + quad * 8);
        bq[g][1] = *(const bf16x8*)(qrow + 32 + quad * 8);
    }

    // all-ones bf16 A fragment for row-sum MFMA
    bf16x8 ones;
#pragma unroll
    for (int e = 0; e < 8; ++e) ones[e] = (short)0x3f80;

    // prefetch tile 0
    stageKV(0, 0);
    __syncthreads();  // KV(0) visible

    f32x4 OA[4], OB[4];
#pragma unroll
    for (int i = 0; i < 4; ++i) {
        OA[i] = (f32x4){0.f, 0.f, 0.f, 0.f};
        OB[i] = (f32x4){0.f, 0.f, 0.f, 0.f};
    }
    f32x4 LA = (f32x4){0.f, 0.f, 0.f, 0.f};
    f32x4 LB = (f32x4){0.f, 0.f, 0.f, 0.f};

    auto tilebody = [&](int t, bool last) {
        const int cur = t & 1;
        if (!last) stageKV(cur ^ 1, t + 1);  // async prefetch
        const u16* ksb = Ks[cur];
        const u16* vsb = Vts[cur];

        // S^T + exp + pack, both q groups sharing K fragments
        uint32_t pk[2][8][2];
#pragma unroll
        for (int nt = 0; nt < 8; ++nt) {
            int rk = nt * 16 + l16;
            bf16x8 ka0 =
                *(const bf16x8*)&ksb[rk * 64 + ((quad ^ (rk & 7)) * 8)];
            bf16x8 ka1 =
                *(const bf16x8*)&ksb[rk * 64 + (((quad + 4) ^ (rk & 7)) * 8)];
#pragma unroll
            for (int g = 0; g < 2; ++g) {
                f32x4 s = (f32x4){0.f, 0.f, 0.f, 0.f};
                s = mfma16(ka0, bq[g][0], s);  // A=K, B=Q -> S^T
                s = mfma16(ka1, bq[g][1], s);
                f32x4 p;
                if (last) {
                    const int kb = t * 128 + nt * 16 + quad * 4;
#pragma unroll
                    for (int r = 0; r < 4; ++r)
                        p[r] = __builtin_amdgcn_exp2f(
                            (kb + r < cn) ? s[r] : -30000.f);
                } else {
#pragma unroll
                    for (int r = 0; r < 4; ++r)
                        p[r] = __builtin_amdgcn_exp2f(s[r]);
                }
                pk[g][nt][0] = pkbf(p[0], p[1]);
                pk[g][nt][1] = pkbf(p[2], p[3]);
            }
        }

        // O^T += V^T·P^T, V fragments shared across both q groups;
        // l += 1^T·P^T on the MFMA pipe
#pragma unroll
        for (int i = 0; i < 4; ++i) {
            union { bf16x8 v; uint32_t u[4]; } bpA, bpB;
            bpA.u[0] = pk[0][2 * i][0];
            bpA.u[1] = pk[0][2 * i][1];
            bpA.u[2] = pk[0][2 * i + 1][0];
            bpA.u[3] = pk[0][2 * i + 1][1];
            bpB.u[0] = pk[1][2 * i][0];
            bpB.u[1] = pk[1][2 * i][1];
            bpB.u[2] = pk[1][2 * i + 1][0];
            bpB.u[3] = pk[1][2 * i + 1][1];
            LA = mfma16(ones, bpA.v, LA);
            LB = mfma16(ones, bpB.v, LB);
#pragma unroll
            for (int dt = 0; dt < 4; ++dt) {
                int vd = dt * 16 + l16;
                bf16x8 ap = *(const bf16x8*)&vsb[vd * 128 +
                                                 (((4 * i + quad) ^ (vd & 15)) *
                                                  8)];
                OA[dt] = mfma16(ap, bpA.v, OA[dt]);
                OB[dt] = mfma16(ap, bpB.v, OB[dt]);
            }
        }

        __syncthreads();  // drains own DMA+ds_reads, then syncs (dbuf safety)
    };

    for (int t = 0; t < ntile - 1; ++t) tilebody(t, false);
    tilebody(ntile - 1, true);

    // epilogue: O[q][d] = O^T[d][q]/l; lane: q=l16, d=dt*16+quad*4+r
    // LA/LB rows are all equal (A=ones), so l = LA[0]/LB[0].
#pragma unroll
    for (int g = 0; g < 2; ++g) {
        float inv = 1.0f / (g == 0 ? LA[0] : LB[0]);
        const f32x4* O = (g == 0) ? OA : OB;
        const int orow = q0 + w * 32 + g * 16 + l16;
#pragma unroll
        for (int dt = 0; dt < 4; ++dt) {
            ushort4 o;
            o.x = f2bf(O[dt][0] * inv);
            o.y = f2bf(O[dt][1] * inv);
            o.z = f2bf(O[dt][2] * inv);
            o.w = f2bf(O[dt][3] * inv);
            *(uint2*)&attnb[head_off + (size_t)orow * EMB + dt * 16 +
                            quad * 4] = *(uint2*)&o;
        }
    }
}

extern "C" void kernel_launch(void* const* d_in, const int* in_sizes, int n_in,
                              void* d_out, int out_size, void* d_ws,
                              size_t ws_size, hipStream_t stream) {
    const float* query = (const float*)d_in[0];
    const float* key = (const float*)d_in[1];
    const float* value = (const float*)d_in[2];
    const int* mask = (const int*)d_in[3];
    const float* Wq = (const float*)d_in[4];
    const float* bq = (const float*)d_in[5];
    const float* Wk = (const float*)d_in[6];
    const float* bk = (const float*)d_in[7];
    const float* Wv = (const float*)d_in[8];
    const float* bv = (const float*)d_in[9];
    const float* Wo = (const float*)d_in[10];
    const float* bo = (const float*)d_in[11];

    char* ws = (char*)d_ws;
    const size_t MB = 1ull << 20;
    u16* xq = (u16*)(ws + 0 * MB);     // 16 MB compacted/cast inputs
    u16* xk = (u16*)(ws + 16 * MB);
    u16* xv = (u16*)(ws + 32 * MB);
    u16* Wqt = (u16*)(ws + 48 * MB);   // 2 MB each
    u16* Wkt = (u16*)(ws + 50 * MB);
    u16* Wvt = (u16*)(ws + 52 * MB);
    u16* Wot = (u16*)(ws + 54 * MB);
    u16* Qp = (u16*)(ws + 56 * MB);
    u16* Kp = (u16*)(ws + 72 * MB);
    u16* Vt = (u16*)(ws + 88 * MB);    // V^T, PV-permuted (written by gemm_qkv)
    u16* attnb = (u16*)(ws + 104 * MB);  // total 120 MB

    // compaction scratch lives in d_out (fully overwritten by O-GEMM later)
    int* cnt = (int*)d_out;                      // 4 ints
    int* idx = (int*)d_out + 64;                 // MTOT ints

    mask_compact<<<BATCH, 256, 0, stream>>>(mask, cnt, idx);

    prep_cast<<<dim3(MTOT, 3), 256, 0, stream>>>(query, key, value, idx, cnt,
                                                 xq, xk, xv);

    transpose_cast4<<<dim3(EMB / 64, EMB / 64, 4), 256, 0, stream>>>(
        Wq, Wk, Wv, Wo, Wqt, Wkt, Wvt, Wot);

    const float c2 = 0.125f * 1.44269504f;  // 1/sqrt(64) * log2(e)
    gemm_qkv<<<dim3(EMB / 128, MTOT / 128, 3), 256, 0, stream>>>(
        xq, xk, xv, Wqt, Wkt, Wvt, bq, bk, bv, Qp, Kp, Vt, cnt, c2);

    attn_kernel<<<BATCH * HEADS * (SEQ / 128), 256, 0, stream>>>(Qp, Kp, Vt,
                                                                 cnt, attnb);

    gemm_bt_f32<<<dim3(EMB / 128, MTOT / 128), 256, 0, stream>>>(
        attnb, Wot, bo, (float*)d_out, EMB);
}